// Round 2
// baseline (2778.299 us; speedup 1.0000x reference)
//
#include <hip/hip_runtime.h>
#include <math.h>

#define NH 8
#define NT 4
#define NR 4
#define MAXLEN 240

typedef __attribute__((ext_vector_type(8))) short bf16x8;
typedef __attribute__((ext_vector_type(4))) float f32x4;

__device__ __forceinline__ unsigned short f2bf(float x) {
    unsigned u = __float_as_uint(x);
    u += 0x7fffu + ((u >> 16) & 1u);
    return (unsigned short)(u >> 16);
}
__device__ __forceinline__ float bflo(unsigned u) { return __uint_as_float(u << 16); }
__device__ __forceinline__ float bfhi(unsigned u) { return __uint_as_float(u & 0xffff0000u); }

__device__ __forceinline__ void atomicMaxF(float* addr, float v) {
    if (v >= 0.f) atomicMax((int*)addr, __float_as_int(v));
    else          atomicMin((unsigned int*)addr, __float_as_uint(v));
}

__global__ void init_kernel(float* mmax, float* den, float* aggr, int n8, int n128) {
    int i = blockIdx.x * blockDim.x + threadIdx.x;
    int stride = gridDim.x * blockDim.x;
    for (int j = i; j < n8; j += stride) { mmax[j] = -INFINITY; den[j] = 0.f; }
    for (int j = i; j < n128; j += stride) aggr[j] = 0.f;
}

// rte_out[m,d] = (sinusoid emb row m) @ rte_W + rte_b   [240,128] f32
__global__ __launch_bounds__(128) void rte_out_kernel(const float* __restrict__ rte_W,
                                                      const float* __restrict__ rte_b,
                                                      float* __restrict__ rte_out) {
    int m = blockIdx.x, d = threadIdx.x;
    __shared__ float emb[128];
    int j2 = d & ~1;
    float div = expf((float)j2 * (-9.210340371976184f / 128.f));
    float ang = (float)m * div;
    float val = ((d & 1) ? cosf(ang) : sinf(ang)) * 0.08838834764831845f;
    emb[d] = val;
    __syncthreads();
    float acc = rte_b[d];
    #pragma unroll 8
    for (int i = 0; i < 128; ++i) acc += emb[i] * rte_W[i * 128 + d];
    rte_out[m * 128 + d] = acc;
}

// krte_bf[t,m,:] = rte_out[m] @ Wk_t (bf16); vmrte_bf[t,r,m,:] = (rte_out[m] @ Wv_t)^T M_r
__global__ __launch_bounds__(128) void rte_tables(
    const float* __restrict__ rte_out, const float* __restrict__ Wk,
    const float* __restrict__ Wv, const float* __restrict__ rel_msg,
    unsigned short* __restrict__ krte_bf, unsigned short* __restrict__ vmrte_bf) {
    int m = blockIdx.x, t = blockIdx.y, d = threadIdx.x;
    __shared__ float sr[128];
    __shared__ float vr[128];
    sr[d] = rte_out[m * 128 + d];
    __syncthreads();
    float ak = 0.f, av = 0.f;
    for (int i = 0; i < 128; ++i) {
        float rv = sr[i];
        ak += rv * Wk[(t * 128 + i) * 128 + d];
        av += rv * Wv[(t * 128 + i) * 128 + d];
    }
    krte_bf[(size_t)(t * MAXLEN + m) * 128 + d] = f2bf(ak);
    vr[d] = av;
    __syncthreads();
    int h = d >> 4, dd = d & 15;
    for (int r = 0; r < NR; ++r) {
        float acc = 0.f;
        #pragma unroll
        for (int k = 0; k < 16; ++k)
            acc += vr[h * 16 + k] * rel_msg[((r * NH + h) * 16 + k) * 16 + dd];
        vmrte_bf[(size_t)((t * 4 + r) * MAXLEN + m) * 128 + d] = f2bf(acc);
    }
}

// Pack Wk/Wq/Wv/Wa into MFMA B-fragment order, bf16.
// PW[set][t][ctg(8)][ks(4)][lane(64)][j(8)];  elem = W[t][ks*32+(lane>>4)*8+j][ctg*16+(lane&15)]
__global__ __launch_bounds__(256) void pack_w(
    const float* __restrict__ Wk, const float* __restrict__ Wq,
    const float* __restrict__ Wv, const float* __restrict__ Wa,
    short* __restrict__ PW) {
    int idx = blockIdx.x * 256 + threadIdx.x;  // 32768 total
    int lane = idx & 63;
    int ks = (idx >> 6) & 3;
    int ctg = (idx >> 8) & 7;
    int t = (idx >> 11) & 3;
    int set = idx >> 13;
    const float* W = set == 0 ? Wk : set == 1 ? Wq : set == 2 ? Wv : Wa;
    const float* Wt = W + t * 16384;
    int col = ctg * 16 + (lane & 15);
    int k0 = ks * 32 + (lane >> 4) * 8;
    unsigned short o[8];
    #pragma unroll
    for (int j = 0; j < 8; ++j) o[j] = f2bf(Wt[(k0 + j) * 128 + col]);
    uint4 pk;
    pk.x = (unsigned)o[0] | ((unsigned)o[1] << 16);
    pk.y = (unsigned)o[2] | ((unsigned)o[3] << 16);
    pk.z = (unsigned)o[4] | ((unsigned)o[5] << 16);
    pk.w = (unsigned)o[6] | ((unsigned)o[7] << 16);
    *reinterpret_cast<uint4*>(PW + (size_t)idx * 8) = pk;
}

// 16 nodes/block, 256 thr. MFMA all 4 types, select per-node type on store.
// Then VALU transforms: qa[n,r,h,k] = pri/4 * sum_d A[r,h,k,d] q[n,h,d];
//                       vm[n,r,h,d] = sum_k v[n,h,k] M[r,h,k,d].  N%16==0 (50000).
__global__ __launch_bounds__(256) void node_kqv_mfma(
    const float* __restrict__ x, const int* __restrict__ ntype,
    const short* __restrict__ PW,
    const float* __restrict__ bk, const float* __restrict__ bq, const float* __restrict__ bv,
    const float* __restrict__ rel_att, const float* __restrict__ rel_msg,
    const float* __restrict__ rel_pri,
    unsigned short* __restrict__ kn_bf, unsigned short* __restrict__ qa_bf,
    unsigned short* __restrict__ vm_bf) {
    __shared__ short xs2[2048];   // [kb(16)][row(16)][j(8)]
    __shared__ float qs[16][128];
    __shared__ float vs[16][128];
    const int tid = threadIdx.x;
    const int nb = blockIdx.x;
    #pragma unroll
    for (int s = 0; s < 8; ++s) {
        int flat = tid + s * 256;
        int ni = flat >> 7, d = flat & 127;
        float v = x[((size_t)nb * 16 + ni) * 128 + d];
        xs2[((d >> 3) * 16 + ni) * 8 + (d & 7)] = (short)f2bf(v);
    }
    __syncthreads();
    const int lane = tid & 63, w = tid >> 6;
    bf16x8 af[4];
    #pragma unroll
    for (int ks = 0; ks < 4; ++ks)
        af[ks] = *reinterpret_cast<const bf16x8*>(&xs2[((ks * 4 + (lane >> 4)) * 16 + (lane & 15)) * 8]);
    const int row0 = (lane >> 4) * 4;
    int types[4];
    #pragma unroll
    for (int j = 0; j < 4; ++j) types[j] = ntype[nb * 16 + row0 + j];

    for (int set = 0; set < 3; ++set) {
        const float* bias = set == 0 ? bk : (set == 1 ? bq : bv);
        for (int t = 0; t < NT; ++t) {
            #pragma unroll
            for (int ctl = 0; ctl < 2; ++ctl) {
                int ctg = w * 2 + ctl;
                f32x4 acc = {0.f, 0.f, 0.f, 0.f};
                #pragma unroll
                for (int ks = 0; ks < 4; ++ks) {
                    bf16x8 bfrag = *reinterpret_cast<const bf16x8*>(
                        PW + ((size_t)((((set * 4 + t) * 8 + ctg) * 4 + ks) * 64 + lane)) * 8);
                    acc = __builtin_amdgcn_mfma_f32_16x16x32_bf16(af[ks], bfrag, acc, 0, 0, 0);
                }
                int col = ctg * 16 + (lane & 15);
                float bval = bias[t * 128 + col];
                #pragma unroll
                for (int j = 0; j < 4; ++j) {
                    if (types[j] == t) {
                        float val = acc[j] + bval;
                        int rowj = row0 + j;
                        if (set == 0)
                            kn_bf[((size_t)nb * 16 + rowj) * 128 + col] = f2bf(val);
                        else if (set == 1) qs[rowj][col] = val;
                        else vs[rowj][col] = val;
                    }
                }
            }
        }
    }
    __syncthreads();
    const int hk = tid & 127, half = tid >> 7;
    const int h = hk >> 4, kk = hk & 15;
    for (int r = 0; r < NR; ++r) {
        float scale = rel_pri[r * NH + h] * 0.25f;
        float acc[8] = {0.f, 0.f, 0.f, 0.f, 0.f, 0.f, 0.f, 0.f};
        for (int dp = 0; dp < 16; ++dp) {
            float a = rel_att[((r * NH + h) * 16 + kk) * 16 + dp];
            #pragma unroll
            for (int n8 = 0; n8 < 8; ++n8)
                acc[n8] += qs[half * 8 + n8][h * 16 + dp] * a;
        }
        #pragma unroll
        for (int n8 = 0; n8 < 8; ++n8) {
            size_t node = (size_t)nb * 16 + half * 8 + n8;
            qa_bf[(node * 4 + r) * 128 + hk] = f2bf(acc[n8] * scale);
        }
        float accv[8] = {0.f, 0.f, 0.f, 0.f, 0.f, 0.f, 0.f, 0.f};
        for (int kp = 0; kp < 16; ++kp) {
            float mm = rel_msg[((r * NH + h) * 16 + kp) * 16 + kk];
            #pragma unroll
            for (int n8 = 0; n8 < 8; ++n8)
                accv[n8] += vs[half * 8 + n8][h * 16 + kp] * mm;
        }
        #pragma unroll
        for (int n8 = 0; n8 < 8; ++n8) {
            size_t node = (size_t)nb * 16 + half * 8 + n8;
            vm_bf[(node * 4 + r) * 128 + hk] = f2bf(accv[n8]);
        }
    }
}

// 16 edges/block, 16 lanes/edge. logit_h = sum (kn[src]+krte[st,tm]) * qa[tgt,r]
__global__ __launch_bounds__(256) void edge_logits2(
    const int* __restrict__ ei, const int* __restrict__ etype,
    const int* __restrict__ etime, const int* __restrict__ ntype,
    const unsigned short* __restrict__ kn_bf, const unsigned short* __restrict__ krte_bf,
    const unsigned short* __restrict__ qa_bf,
    float* __restrict__ logits, float* __restrict__ mmax, int E) {
    int e = blockIdx.x * 16 + (threadIdx.x >> 4);
    int l16 = threadIdx.x & 15;
    if (e >= E) return;
    int src = ei[e], tgt = ei[E + e];
    int r = etype[e], tm = etime[e], st = ntype[src];
    uint4 kv = *reinterpret_cast<const uint4*>(kn_bf + (size_t)src * 128 + l16 * 8);
    uint4 kr = *reinterpret_cast<const uint4*>(krte_bf + (size_t)(st * MAXLEN + tm) * 128 + l16 * 8);
    uint4 qv = *reinterpret_cast<const uint4*>(qa_bf + ((size_t)tgt * 4 + r) * 128 + l16 * 8);
    unsigned ku[4] = {kv.x, kv.y, kv.z, kv.w};
    unsigned ru[4] = {kr.x, kr.y, kr.z, kr.w};
    unsigned qu[4] = {qv.x, qv.y, qv.z, qv.w};
    float p = 0.f;
    #pragma unroll
    for (int c = 0; c < 4; ++c) {
        p += (bflo(ku[c]) + bflo(ru[c])) * bflo(qu[c]);
        p += (bfhi(ku[c]) + bfhi(ru[c])) * bfhi(qu[c]);
    }
    p += __shfl_xor(p, 1);
    if ((l16 & 1) == 0) {
        int h = l16 >> 1;
        logits[(size_t)e * NH + h] = p;
        atomicMaxF(&mmax[(size_t)tgt * NH + h], p);
    }
}

__global__ void edge_exp_kernel(const int* __restrict__ ei, float* __restrict__ logits,
                                const float* __restrict__ mmax, float* __restrict__ den, int E) {
    int i = blockIdx.x * blockDim.x + threadIdx.x;
    if (i >= E * NH) return;
    int e = i >> 3, h = i & 7;
    int tgt = ei[E + e];
    float ex = expf(logits[i] - mmax[(size_t)tgt * NH + h]);
    logits[i] = ex;
    unsafeAtomicAdd(&den[(size_t)tgt * NH + h], ex);
}

__global__ __launch_bounds__(256) void edge_aggr2(
    const int* __restrict__ ei, const int* __restrict__ etype,
    const int* __restrict__ etime, const int* __restrict__ ntype,
    const unsigned short* __restrict__ vm_bf, const unsigned short* __restrict__ vmrte_bf,
    const float* __restrict__ ex, const float* __restrict__ den,
    float* __restrict__ aggr, int E) {
    int e = blockIdx.x * 16 + (threadIdx.x >> 4);
    int l16 = threadIdx.x & 15;
    if (e >= E) return;
    int src = ei[e], tgt = ei[E + e];
    int r = etype[e], tm = etime[e], st = ntype[src];
    int h = l16 >> 1;
    uint4 mv = *reinterpret_cast<const uint4*>(vm_bf + ((size_t)src * 4 + r) * 128 + l16 * 8);
    uint4 mr = *reinterpret_cast<const uint4*>(vmrte_bf + (size_t)((st * 4 + r) * MAXLEN + tm) * 128 + l16 * 8);
    float att = ex[(size_t)e * NH + h] / den[(size_t)tgt * NH + h];
    float* ap = aggr + (size_t)tgt * 128 + l16 * 8;
    unsigned mu_[4] = {mv.x, mv.y, mv.z, mv.w};
    unsigned ru[4] = {mr.x, mr.y, mr.z, mr.w};
    #pragma unroll
    for (int c = 0; c < 4; ++c) {
        unsafeAtomicAdd(ap + 2 * c,     (bflo(mu_[c]) + bflo(ru[c])) * att);
        unsafeAtomicAdd(ap + 2 * c + 1, (bfhi(mu_[c]) + bfhi(ru[c])) * att);
    }
}

// 16 nodes/block: gelu(aggr) -> bf16 -> MFMA vs Wa (all types, select) -> skip-blend -> LN
__global__ __launch_bounds__(256) void node_update_mfma(
    const float* __restrict__ x, const int* __restrict__ ntype,
    const float* __restrict__ aggr, const short* __restrict__ PW,
    const float* __restrict__ ba, const float* __restrict__ gamma,
    const float* __restrict__ beta, const float* __restrict__ skip,
    float* __restrict__ out) {
    __shared__ short xs2[2048];
    __shared__ float hs[16][128];
    const int tid = threadIdx.x;
    const int nb = blockIdx.x;
    #pragma unroll
    for (int s = 0; s < 8; ++s) {
        int flat = tid + s * 256;
        int ni = flat >> 7, d = flat & 127;
        float v = aggr[((size_t)nb * 16 + ni) * 128 + d];
        float g = 0.5f * v * (1.f + erff(v * 0.7071067811865476f));
        xs2[((d >> 3) * 16 + ni) * 8 + (d & 7)] = (short)f2bf(g);
    }
    __syncthreads();
    const int lane = tid & 63, w = tid >> 6;
    bf16x8 af[4];
    #pragma unroll
    for (int ks = 0; ks < 4; ++ks)
        af[ks] = *reinterpret_cast<const bf16x8*>(&xs2[((ks * 4 + (lane >> 4)) * 16 + (lane & 15)) * 8]);
    const int row0 = (lane >> 4) * 4;
    int types[4];
    #pragma unroll
    for (int j = 0; j < 4; ++j) types[j] = ntype[nb * 16 + row0 + j];

    for (int t = 0; t < NT; ++t) {
        float alpha = 1.f / (1.f + expf(-skip[t]));
        #pragma unroll
        for (int ctl = 0; ctl < 2; ++ctl) {
            int ctg = w * 2 + ctl;
            f32x4 acc = {0.f, 0.f, 0.f, 0.f};
            #pragma unroll
            for (int ks = 0; ks < 4; ++ks) {
                bf16x8 bfrag = *reinterpret_cast<const bf16x8*>(
                    PW + ((size_t)((((3 * 4 + t) * 8 + ctg) * 4 + ks) * 64 + lane)) * 8);
                acc = __builtin_amdgcn_mfma_f32_16x16x32_bf16(af[ks], bfrag, acc, 0, 0, 0);
            }
            int col = ctg * 16 + (lane & 15);
            float bval = ba[t * 128 + col];
            #pragma unroll
            for (int j = 0; j < 4; ++j) {
                if (types[j] == t) {
                    int rowj = row0 + j;
                    float tr = acc[j] + bval;
                    float xv = x[((size_t)nb * 16 + rowj) * 128 + col];
                    hs[rowj][col] = tr * alpha + xv * (1.f - alpha);
                }
            }
        }
    }
    __syncthreads();
    const int node = tid >> 4, l16 = tid & 15;
    float s1 = 0.f, s2 = 0.f;
    float hv[8];
    #pragma unroll
    for (int j = 0; j < 8; ++j) {
        hv[j] = hs[node][l16 * 8 + j];
        s1 += hv[j];
        s2 += hv[j] * hv[j];
    }
    #pragma unroll
    for (int off = 1; off < 16; off <<= 1) {
        s1 += __shfl_xor(s1, off);
        s2 += __shfl_xor(s2, off);
    }
    float mu = s1 * (1.f / 128.f);
    float var = s2 * (1.f / 128.f) - mu * mu;
    float inv = 1.f / sqrtf(var + 1e-5f);
    int t = ntype[nb * 16 + node];
    #pragma unroll
    for (int j = 0; j < 8; ++j) {
        int d = l16 * 8 + j;
        out[((size_t)nb * 16 + node) * 128 + d] = (hv[j] - mu) * inv * gamma[t * 128 + d] + beta[t * 128 + d];
    }
}

extern "C" void kernel_launch(void* const* d_in, const int* in_sizes, int n_in,
                              void* d_out, int out_size, void* d_ws, size_t ws_size,
                              hipStream_t stream) {
    const float* node_inp = (const float*)d_in[0];
    const int*   node_type = (const int*)d_in[1];
    const int*   edge_index = (const int*)d_in[2];
    const int*   edge_type = (const int*)d_in[3];
    const int*   edge_time = (const int*)d_in[4];
    const float* Wk = (const float*)d_in[5];
    const float* bk = (const float*)d_in[6];
    const float* Wq = (const float*)d_in[7];
    const float* bq = (const float*)d_in[8];
    const float* Wv = (const float*)d_in[9];
    const float* bv = (const float*)d_in[10];
    const float* Wa = (const float*)d_in[11];
    const float* ba = (const float*)d_in[12];
    const float* gamma = (const float*)d_in[13];
    const float* beta = (const float*)d_in[14];
    const float* rel_pri = (const float*)d_in[15];
    const float* rel_att = (const float*)d_in[16];
    const float* rel_msg = (const float*)d_in[17];
    const float* skip = (const float*)d_in[18];
    const float* rte_W = (const float*)d_in[19];
    const float* rte_b = (const float*)d_in[20];

    int N = in_sizes[0] / 128;   // 50000, N % 16 == 0
    int E = in_sizes[3];         // 600000

    char* base = (char*)d_ws;
    float* aggr = (float*)base;               base += (size_t)N * 128 * 4;
    float* mmax = (float*)base;               base += (size_t)N * NH * 4;
    float* den  = (float*)base;               base += (size_t)N * NH * 4;
    float* logits = (float*)base;             base += (size_t)E * NH * 4;
    float* rte_out = (float*)base;            base += (size_t)MAXLEN * 128 * 4;
    unsigned short* kn_bf = (unsigned short*)base;    base += (size_t)N * 128 * 2;
    unsigned short* qa_bf = (unsigned short*)base;    base += (size_t)N * 4 * 128 * 2;
    unsigned short* vm_bf = (unsigned short*)base;    base += (size_t)N * 4 * 128 * 2;
    unsigned short* krte_bf = (unsigned short*)base;  base += (size_t)NT * MAXLEN * 128 * 2;
    unsigned short* vmrte_bf = (unsigned short*)base; base += (size_t)NT * NR * MAXLEN * 128 * 2;
    short* PW = (short*)base;                 base += (size_t)4 * NT * 128 * 128 * 2;

    init_kernel<<<1024, 256, 0, stream>>>(mmax, den, aggr, N * NH, N * 128);
    rte_out_kernel<<<MAXLEN, 128, 0, stream>>>(rte_W, rte_b, rte_out);
    dim3 gt(MAXLEN, NT);
    rte_tables<<<gt, 128, 0, stream>>>(rte_out, Wk, Wv, rel_msg, krte_bf, vmrte_bf);
    pack_w<<<128, 256, 0, stream>>>(Wk, Wq, Wv, Wa, PW);
    node_kqv_mfma<<<N / 16, 256, 0, stream>>>(node_inp, node_type, PW, bk, bq, bv,
                                              rel_att, rel_msg, rel_pri,
                                              kn_bf, qa_bf, vm_bf);
    edge_logits2<<<(E + 15) / 16, 256, 0, stream>>>(edge_index, edge_type, edge_time, node_type,
                                                    kn_bf, krte_bf, qa_bf, logits, mmax, E);
    edge_exp_kernel<<<(E * NH + 255) / 256, 256, 0, stream>>>(edge_index, logits, mmax, den, E);
    edge_aggr2<<<(E + 15) / 16, 256, 0, stream>>>(edge_index, edge_type, edge_time, node_type,
                                                  vm_bf, vmrte_bf, logits, den, aggr, E);
    node_update_mfma<<<N / 16, 256, 0, stream>>>(node_inp, node_type, aggr, PW, ba,
                                                 gamma, beta, skip, (float*)d_out);
}

// Round 3
// 695.044 us; speedup vs baseline: 3.9973x; 3.9973x over previous
//
#include <hip/hip_runtime.h>
#include <math.h>

#define NH 8
#define NT 4
#define NR 4
#define MAXLEN 240

typedef __attribute__((ext_vector_type(8))) short bf16x8;
typedef __attribute__((ext_vector_type(4))) float f32x4;

__device__ __forceinline__ unsigned short f2bf(float x) {
    unsigned u = __float_as_uint(x);
    u += 0x7fffu + ((u >> 16) & 1u);
    return (unsigned short)(u >> 16);
}
__device__ __forceinline__ float bflo(unsigned u) { return __uint_as_float(u << 16); }
__device__ __forceinline__ float bfhi(unsigned u) { return __uint_as_float(u & 0xffff0000u); }

__global__ void zero_kernel(int* deg, int* cursor, int N) {
    int i = blockIdx.x * blockDim.x + threadIdx.x;
    int stride = gridDim.x * blockDim.x;
    for (int j = i; j < N; j += stride) { deg[j] = 0; cursor[j] = 0; }
}

__global__ void deg_kernel(const int* __restrict__ ei, int* __restrict__ deg, int E) {
    int i = blockIdx.x * blockDim.x + threadIdx.x;
    int stride = gridDim.x * blockDim.x;
    for (int e = i; e < E; e += stride) atomicAdd(&deg[ei[E + e]], 1);
}

__global__ __launch_bounds__(256) void scanA(const int* __restrict__ deg, int* __restrict__ excl,
                                             int* __restrict__ bsum, int N) {
    __shared__ int tmp[256];
    int i = blockIdx.x * 256 + threadIdx.x;
    int v = i < N ? deg[i] : 0;
    tmp[threadIdx.x] = v;
    __syncthreads();
    #pragma unroll
    for (int off = 1; off < 256; off <<= 1) {
        int t = threadIdx.x >= off ? tmp[threadIdx.x - off] : 0;
        __syncthreads();
        tmp[threadIdx.x] += t;
        __syncthreads();
    }
    if (i < N) excl[i] = tmp[threadIdx.x] - v;
    if (threadIdx.x == 255) bsum[blockIdx.x] = tmp[255];
}

__global__ __launch_bounds__(256) void scanB(int* __restrict__ bsum, int nb) {
    __shared__ int tmp[256];
    int v = threadIdx.x < nb ? bsum[threadIdx.x] : 0;
    tmp[threadIdx.x] = v;
    __syncthreads();
    #pragma unroll
    for (int off = 1; off < 256; off <<= 1) {
        int t = threadIdx.x >= off ? tmp[threadIdx.x - off] : 0;
        __syncthreads();
        tmp[threadIdx.x] += t;
        __syncthreads();
    }
    if (threadIdx.x < nb) bsum[threadIdx.x] = tmp[threadIdx.x] - v;
}

__global__ void scanC(const int* __restrict__ excl, const int* __restrict__ bsum,
                      int* __restrict__ row_start, int N) {
    int i = blockIdx.x * blockDim.x + threadIdx.x;
    if (i < N) row_start[i] = excl[i] + bsum[i >> 8];
}

__global__ void scatter_kernel(const int* __restrict__ ei, const int* __restrict__ etype,
                               const int* __restrict__ etime, const int* __restrict__ ntype,
                               const int* __restrict__ row_start, int* __restrict__ cursor,
                               int2* __restrict__ ebuf, int E) {
    int i = blockIdx.x * blockDim.x + threadIdx.x;
    int stride = gridDim.x * blockDim.x;
    for (int e = i; e < E; e += stride) {
        int src = ei[e], tgt = ei[E + e];
        int pos = atomicAdd(&cursor[tgt], 1);
        int2 v;
        v.x = src;
        v.y = etype[e] | (etime[e] << 2) | (ntype[src] << 10);
        ebuf[row_start[tgt] + pos] = v;
    }
}

// rte_out[m,d] = (sinusoid emb row m) @ rte_W + rte_b   [240,128] f32
__global__ __launch_bounds__(128) void rte_out_kernel(const float* __restrict__ rte_W,
                                                      const float* __restrict__ rte_b,
                                                      float* __restrict__ rte_out) {
    int m = blockIdx.x, d = threadIdx.x;
    __shared__ float emb[128];
    int j2 = d & ~1;
    float div = expf((float)j2 * (-9.210340371976184f / 128.f));
    float ang = (float)m * div;
    float val = ((d & 1) ? cosf(ang) : sinf(ang)) * 0.08838834764831845f;
    emb[d] = val;
    __syncthreads();
    float acc = rte_b[d];
    #pragma unroll 8
    for (int i = 0; i < 128; ++i) acc += emb[i] * rte_W[i * 128 + d];
    rte_out[m * 128 + d] = acc;
}

// krte_bf[t,m,:] = rte_out[m] @ Wk_t (bf16); vmrte_bf[t,r,m,:] = (rte_out[m] @ Wv_t)^T M_r
__global__ __launch_bounds__(128) void rte_tables(
    const float* __restrict__ rte_out, const float* __restrict__ Wk,
    const float* __restrict__ Wv, const float* __restrict__ rel_msg,
    unsigned short* __restrict__ krte_bf, unsigned short* __restrict__ vmrte_bf) {
    int m = blockIdx.x, t = blockIdx.y, d = threadIdx.x;
    __shared__ float sr[128];
    __shared__ float vr[128];
    sr[d] = rte_out[m * 128 + d];
    __syncthreads();
    float ak = 0.f, av = 0.f;
    for (int i = 0; i < 128; ++i) {
        float rv = sr[i];
        ak += rv * Wk[(t * 128 + i) * 128 + d];
        av += rv * Wv[(t * 128 + i) * 128 + d];
    }
    krte_bf[(size_t)(t * MAXLEN + m) * 128 + d] = f2bf(ak);
    vr[d] = av;
    __syncthreads();
    int h = d >> 4, dd = d & 15;
    for (int r = 0; r < NR; ++r) {
        float acc = 0.f;
        #pragma unroll
        for (int k = 0; k < 16; ++k)
            acc += vr[h * 16 + k] * rel_msg[((r * NH + h) * 16 + k) * 16 + dd];
        vmrte_bf[(size_t)((t * 4 + r) * MAXLEN + m) * 128 + d] = f2bf(acc);
    }
}

// Pack Wk/Wq/Wv/Wa into MFMA B-fragment order, bf16.
__global__ __launch_bounds__(256) void pack_w(
    const float* __restrict__ Wk, const float* __restrict__ Wq,
    const float* __restrict__ Wv, const float* __restrict__ Wa,
    short* __restrict__ PW) {
    int idx = blockIdx.x * 256 + threadIdx.x;  // 32768 total
    int lane = idx & 63;
    int ks = (idx >> 6) & 3;
    int ctg = (idx >> 8) & 7;
    int t = (idx >> 11) & 3;
    int set = idx >> 13;
    const float* W = set == 0 ? Wk : set == 1 ? Wq : set == 2 ? Wv : Wa;
    const float* Wt = W + t * 16384;
    int col = ctg * 16 + (lane & 15);
    int k0 = ks * 32 + (lane >> 4) * 8;
    unsigned short o[8];
    #pragma unroll
    for (int j = 0; j < 8; ++j) o[j] = f2bf(Wt[(k0 + j) * 128 + col]);
    uint4 pk;
    pk.x = (unsigned)o[0] | ((unsigned)o[1] << 16);
    pk.y = (unsigned)o[2] | ((unsigned)o[3] << 16);
    pk.z = (unsigned)o[4] | ((unsigned)o[5] << 16);
    pk.w = (unsigned)o[6] | ((unsigned)o[7] << 16);
    *reinterpret_cast<uint4*>(PW + (size_t)idx * 8) = pk;
}

// 16 nodes/block: MFMA K/Q/V for all 4 types, select per-node type; then fold
// rel_att into q (qa) and rel_msg into v (vm).
__global__ __launch_bounds__(256) void node_kqv_mfma(
    const float* __restrict__ x, const int* __restrict__ ntype,
    const short* __restrict__ PW,
    const float* __restrict__ bk, const float* __restrict__ bq, const float* __restrict__ bv,
    const float* __restrict__ rel_att, const float* __restrict__ rel_msg,
    const float* __restrict__ rel_pri,
    unsigned short* __restrict__ kn_bf, unsigned short* __restrict__ qa_bf,
    unsigned short* __restrict__ vm_bf) {
    __shared__ short xs2[2048];   // [kb(16)][row(16)][j(8)]
    __shared__ float qs[16][128];
    __shared__ float vs[16][128];
    const int tid = threadIdx.x;
    const int nb = blockIdx.x;
    #pragma unroll
    for (int s = 0; s < 8; ++s) {
        int flat = tid + s * 256;
        int ni = flat >> 7, d = flat & 127;
        float v = x[((size_t)nb * 16 + ni) * 128 + d];
        xs2[((d >> 3) * 16 + ni) * 8 + (d & 7)] = (short)f2bf(v);
    }
    __syncthreads();
    const int lane = tid & 63, w = tid >> 6;
    bf16x8 af[4];
    #pragma unroll
    for (int ks = 0; ks < 4; ++ks)
        af[ks] = *reinterpret_cast<const bf16x8*>(&xs2[((ks * 4 + (lane >> 4)) * 16 + (lane & 15)) * 8]);
    const int row0 = (lane >> 4) * 4;
    int types[4];
    #pragma unroll
    for (int j = 0; j < 4; ++j) types[j] = ntype[nb * 16 + row0 + j];

    for (int set = 0; set < 3; ++set) {
        const float* bias = set == 0 ? bk : (set == 1 ? bq : bv);
        for (int t = 0; t < NT; ++t) {
            #pragma unroll
            for (int ctl = 0; ctl < 2; ++ctl) {
                int ctg = w * 2 + ctl;
                f32x4 acc = {0.f, 0.f, 0.f, 0.f};
                #pragma unroll
                for (int ks = 0; ks < 4; ++ks) {
                    bf16x8 bfrag = *reinterpret_cast<const bf16x8*>(
                        PW + ((size_t)((((set * 4 + t) * 8 + ctg) * 4 + ks) * 64 + lane)) * 8);
                    acc = __builtin_amdgcn_mfma_f32_16x16x32_bf16(af[ks], bfrag, acc, 0, 0, 0);
                }
                int col = ctg * 16 + (lane & 15);
                float bval = bias[t * 128 + col];
                #pragma unroll
                for (int j = 0; j < 4; ++j) {
                    if (types[j] == t) {
                        float val = acc[j] + bval;
                        int rowj = row0 + j;
                        if (set == 0)
                            kn_bf[((size_t)nb * 16 + rowj) * 128 + col] = f2bf(val);
                        else if (set == 1) qs[rowj][col] = val;
                        else vs[rowj][col] = val;
                    }
                }
            }
        }
    }
    __syncthreads();
    const int hk = tid & 127, half = tid >> 7;
    const int h = hk >> 4, kk = hk & 15;
    for (int r = 0; r < NR; ++r) {
        float scale = rel_pri[r * NH + h] * 0.25f;
        float acc[8] = {0.f, 0.f, 0.f, 0.f, 0.f, 0.f, 0.f, 0.f};
        for (int dp = 0; dp < 16; ++dp) {
            float a = rel_att[((r * NH + h) * 16 + kk) * 16 + dp];
            #pragma unroll
            for (int n8 = 0; n8 < 8; ++n8)
                acc[n8] += qs[half * 8 + n8][h * 16 + dp] * a;
        }
        #pragma unroll
        for (int n8 = 0; n8 < 8; ++n8) {
            size_t node = (size_t)nb * 16 + half * 8 + n8;
            qa_bf[(node * 4 + r) * 128 + hk] = f2bf(acc[n8] * scale);
        }
        float accv[8] = {0.f, 0.f, 0.f, 0.f, 0.f, 0.f, 0.f, 0.f};
        for (int kp = 0; kp < 16; ++kp) {
            float mm = rel_msg[((r * NH + h) * 16 + kp) * 16 + kk];
            #pragma unroll
            for (int n8 = 0; n8 < 8; ++n8)
                accv[n8] += vs[half * 8 + n8][h * 16 + kp] * mm;
        }
        #pragma unroll
        for (int n8 = 0; n8 < 8; ++n8) {
            size_t node = (size_t)nb * 16 + half * 8 + n8;
            vm_bf[(node * 4 + r) * 128 + hk] = f2bf(accv[n8]);
        }
    }
}

// One node per 16 lanes. CSR edges; online softmax per head; f32 accum; no atomics.
__global__ __launch_bounds__(256) void fused_edge_attn(
    const int2* __restrict__ ebuf, const int* __restrict__ row_start, const int* __restrict__ deg,
    const unsigned short* __restrict__ kn_bf, const unsigned short* __restrict__ krte_bf,
    const unsigned short* __restrict__ qa_bf, const unsigned short* __restrict__ vm_bf,
    const unsigned short* __restrict__ vmrte_bf,
    float* __restrict__ aggr, int N) {
    int node = blockIdx.x * 16 + (threadIdx.x >> 4);
    int l16 = threadIdx.x & 15;
    if (node >= N) return;
    uint4 q[4];
    #pragma unroll
    for (int r = 0; r < 4; ++r)
        q[r] = *reinterpret_cast<const uint4*>(qa_bf + ((size_t)node * 4 + r) * 128 + l16 * 8);
    int start = row_start[node], cnt = deg[node];
    float m = -INFINITY, den = 0.f;
    float acc[8] = {0.f, 0.f, 0.f, 0.f, 0.f, 0.f, 0.f, 0.f};
    for (int i = 0; i < cnt; ++i) {
        int2 em = ebuf[start + i];
        int src = em.x;
        int r = em.y & 3, tm = (em.y >> 2) & 255, st = (em.y >> 10) & 3;
        uint4 kv = *reinterpret_cast<const uint4*>(kn_bf + (size_t)src * 128 + l16 * 8);
        uint4 kr = *reinterpret_cast<const uint4*>(krte_bf + (size_t)(st * MAXLEN + tm) * 128 + l16 * 8);
        uint4 qr = q[r];
        float p = 0.f;
        p += (bflo(kv.x) + bflo(kr.x)) * bflo(qr.x);
        p += (bfhi(kv.x) + bfhi(kr.x)) * bfhi(qr.x);
        p += (bflo(kv.y) + bflo(kr.y)) * bflo(qr.y);
        p += (bfhi(kv.y) + bfhi(kr.y)) * bfhi(qr.y);
        p += (bflo(kv.z) + bflo(kr.z)) * bflo(qr.z);
        p += (bfhi(kv.z) + bfhi(kr.z)) * bfhi(qr.z);
        p += (bflo(kv.w) + bflo(kr.w)) * bflo(qr.w);
        p += (bfhi(kv.w) + bfhi(kr.w)) * bfhi(qr.w);
        p += __shfl_xor(p, 1);  // head logit; lane pair (2h,2h+1) both hold it
        uint4 mv = *reinterpret_cast<const uint4*>(vm_bf + ((size_t)src * 4 + r) * 128 + l16 * 8);
        uint4 mr = *reinterpret_cast<const uint4*>(vmrte_bf + (size_t)((st * 4 + r) * MAXLEN + tm) * 128 + l16 * 8);
        float mnew = fmaxf(m, p);
        float s = __expf(m - mnew);     // 0 on first edge (m = -inf)
        float wgt = __expf(p - mnew);
        den = den * s + wgt;
        acc[0] = acc[0] * s + wgt * (bflo(mv.x) + bflo(mr.x));
        acc[1] = acc[1] * s + wgt * (bfhi(mv.x) + bfhi(mr.x));
        acc[2] = acc[2] * s + wgt * (bflo(mv.y) + bflo(mr.y));
        acc[3] = acc[3] * s + wgt * (bfhi(mv.y) + bfhi(mr.y));
        acc[4] = acc[4] * s + wgt * (bflo(mv.z) + bflo(mr.z));
        acc[5] = acc[5] * s + wgt * (bfhi(mv.z) + bfhi(mr.z));
        acc[6] = acc[6] * s + wgt * (bflo(mv.w) + bflo(mr.w));
        acc[7] = acc[7] * s + wgt * (bfhi(mv.w) + bfhi(mr.w));
        m = mnew;
    }
    float inv = den > 0.f ? 1.f / den : 0.f;
    float4 o0, o1;
    o0.x = acc[0] * inv; o0.y = acc[1] * inv; o0.z = acc[2] * inv; o0.w = acc[3] * inv;
    o1.x = acc[4] * inv; o1.y = acc[5] * inv; o1.z = acc[6] * inv; o1.w = acc[7] * inv;
    float* ap = aggr + (size_t)node * 128 + l16 * 8;
    *reinterpret_cast<float4*>(ap) = o0;
    *reinterpret_cast<float4*>(ap + 4) = o1;
}

// 16 nodes/block: gelu(aggr) -> bf16 -> MFMA vs Wa (all types, select) -> skip-blend -> LN
__global__ __launch_bounds__(256) void node_update_mfma(
    const float* __restrict__ x, const int* __restrict__ ntype,
    const float* __restrict__ aggr, const short* __restrict__ PW,
    const float* __restrict__ ba, const float* __restrict__ gamma,
    const float* __restrict__ beta, const float* __restrict__ skip,
    float* __restrict__ out) {
    __shared__ short xs2[2048];
    __shared__ float hs[16][128];
    const int tid = threadIdx.x;
    const int nb = blockIdx.x;
    #pragma unroll
    for (int s = 0; s < 8; ++s) {
        int flat = tid + s * 256;
        int ni = flat >> 7, d = flat & 127;
        float v = aggr[((size_t)nb * 16 + ni) * 128 + d];
        float g = 0.5f * v * (1.f + erff(v * 0.7071067811865476f));
        xs2[((d >> 3) * 16 + ni) * 8 + (d & 7)] = (short)f2bf(g);
    }
    __syncthreads();
    const int lane = tid & 63, w = tid >> 6;
    bf16x8 af[4];
    #pragma unroll
    for (int ks = 0; ks < 4; ++ks)
        af[ks] = *reinterpret_cast<const bf16x8*>(&xs2[((ks * 4 + (lane >> 4)) * 16 + (lane & 15)) * 8]);
    const int row0 = (lane >> 4) * 4;
    int types[4];
    #pragma unroll
    for (int j = 0; j < 4; ++j) types[j] = ntype[nb * 16 + row0 + j];

    for (int t = 0; t < NT; ++t) {
        float alpha = 1.f / (1.f + expf(-skip[t]));
        #pragma unroll
        for (int ctl = 0; ctl < 2; ++ctl) {
            int ctg = w * 2 + ctl;
            f32x4 acc = {0.f, 0.f, 0.f, 0.f};
            #pragma unroll
            for (int ks = 0; ks < 4; ++ks) {
                bf16x8 bfrag = *reinterpret_cast<const bf16x8*>(
                    PW + ((size_t)((((3 * 4 + t) * 8 + ctg) * 4 + ks) * 64 + lane)) * 8);
                acc = __builtin_amdgcn_mfma_f32_16x16x32_bf16(af[ks], bfrag, acc, 0, 0, 0);
            }
            int col = ctg * 16 + (lane & 15);
            float bval = ba[t * 128 + col];
            #pragma unroll
            for (int j = 0; j < 4; ++j) {
                if (types[j] == t) {
                    int rowj = row0 + j;
                    float tr = acc[j] + bval;
                    float xv = x[((size_t)nb * 16 + rowj) * 128 + col];
                    hs[rowj][col] = tr * alpha + xv * (1.f - alpha);
                }
            }
        }
    }
    __syncthreads();
    const int node = tid >> 4, l16 = tid & 15;
    float s1 = 0.f, s2 = 0.f;
    float hv[8];
    #pragma unroll
    for (int j = 0; j < 8; ++j) {
        hv[j] = hs[node][l16 * 8 + j];
        s1 += hv[j];
        s2 += hv[j] * hv[j];
    }
    #pragma unroll
    for (int off = 1; off < 16; off <<= 1) {
        s1 += __shfl_xor(s1, off);
        s2 += __shfl_xor(s2, off);
    }
    float mu = s1 * (1.f / 128.f);
    float var = s2 * (1.f / 128.f) - mu * mu;
    float inv = 1.f / sqrtf(var + 1e-5f);
    int t = ntype[nb * 16 + node];
    #pragma unroll
    for (int j = 0; j < 8; ++j) {
        int d = l16 * 8 + j;
        out[((size_t)nb * 16 + node) * 128 + d] = (hv[j] - mu) * inv * gamma[t * 128 + d] + beta[t * 128 + d];
    }
}

extern "C" void kernel_launch(void* const* d_in, const int* in_sizes, int n_in,
                              void* d_out, int out_size, void* d_ws, size_t ws_size,
                              hipStream_t stream) {
    const float* node_inp = (const float*)d_in[0];
    const int*   node_type = (const int*)d_in[1];
    const int*   edge_index = (const int*)d_in[2];
    const int*   edge_type = (const int*)d_in[3];
    const int*   edge_time = (const int*)d_in[4];
    const float* Wk = (const float*)d_in[5];
    const float* bk = (const float*)d_in[6];
    const float* Wq = (const float*)d_in[7];
    const float* bq = (const float*)d_in[8];
    const float* Wv = (const float*)d_in[9];
    const float* bv = (const float*)d_in[10];
    const float* Wa = (const float*)d_in[11];
    const float* ba = (const float*)d_in[12];
    const float* gamma = (const float*)d_in[13];
    const float* beta = (const float*)d_in[14];
    const float* rel_pri = (const float*)d_in[15];
    const float* rel_att = (const float*)d_in[16];
    const float* rel_msg = (const float*)d_in[17];
    const float* skip = (const float*)d_in[18];
    const float* rte_W = (const float*)d_in[19];
    const float* rte_b = (const float*)d_in[20];

    int N = in_sizes[0] / 128;   // 50000 (divisible by 16)
    int E = in_sizes[3];         // 600000

    char* base = (char*)d_ws;
    float* aggr = (float*)base;               base += (size_t)N * 128 * 4;
    float* rte_out = (float*)base;            base += (size_t)MAXLEN * 128 * 4;
    unsigned short* kn_bf = (unsigned short*)base;    base += (size_t)N * 128 * 2;
    unsigned short* qa_bf = (unsigned short*)base;    base += (size_t)N * 4 * 128 * 2;
    unsigned short* vm_bf = (unsigned short*)base;    base += (size_t)N * 4 * 128 * 2;
    unsigned short* krte_bf = (unsigned short*)base;  base += (size_t)NT * MAXLEN * 128 * 2;
    unsigned short* vmrte_bf = (unsigned short*)base; base += (size_t)NT * NR * MAXLEN * 128 * 2;
    short* PW = (short*)base;                 base += (size_t)4 * NT * 128 * 128 * 2;
    int* deg = (int*)base;                    base += (size_t)N * 4;
    int* cursor = (int*)base;                 base += (size_t)N * 4;
    int* excl = (int*)base;                   base += (size_t)N * 4;
    int* row_start = (int*)base;              base += (size_t)N * 4;
    int* bsum = (int*)base;                   base += 256 * 4;
    // align to 8 for int2
    base = (char*)(((size_t)base + 15) & ~(size_t)15);
    int2* ebuf = (int2*)base;                 base += (size_t)E * 8;

    int nb = (N + 255) / 256;  // 196 <= 256

    zero_kernel<<<256, 256, 0, stream>>>(deg, cursor, N);
    deg_kernel<<<1024, 256, 0, stream>>>(edge_index, deg, E);
    scanA<<<nb, 256, 0, stream>>>(deg, excl, bsum, N);
    scanB<<<1, 256, 0, stream>>>(bsum, nb);
    scanC<<<nb, 256, 0, stream>>>(excl, bsum, row_start, N);
    scatter_kernel<<<1024, 256, 0, stream>>>(edge_index, edge_type, edge_time, node_type,
                                             row_start, cursor, ebuf, E);
    rte_out_kernel<<<MAXLEN, 128, 0, stream>>>(rte_W, rte_b, rte_out);
    dim3 gt(MAXLEN, NT);
    rte_tables<<<gt, 128, 0, stream>>>(rte_out, Wk, Wv, rel_msg, krte_bf, vmrte_bf);
    pack_w<<<128, 256, 0, stream>>>(Wk, Wq, Wv, Wa, PW);
    node_kqv_mfma<<<N / 16, 256, 0, stream>>>(node_inp, node_type, PW, bk, bq, bv,
                                              rel_att, rel_msg, rel_pri,
                                              kn_bf, qa_bf, vm_bf);
    fused_edge_attn<<<(N + 15) / 16, 256, 0, stream>>>(ebuf, row_start, deg,
                                                       kn_bf, krte_bf, qa_bf, vm_bf, vmrte_bf,
                                                       aggr, N);
    node_update_mfma<<<N / 16, 256, 0, stream>>>(node_inp, node_type, aggr, PW, ba,
                                                 gamma, beta, skip, (float*)d_out);
}

// Round 4
// 368.214 us; speedup vs baseline: 7.5453x; 1.8876x over previous
//
#include <hip/hip_runtime.h>
#include <math.h>

#define NH 8
#define NT 4
#define NR 4
#define MAXLEN 240

typedef __attribute__((ext_vector_type(8))) short bf16x8;
typedef __attribute__((ext_vector_type(4))) float f32x4;

__device__ __forceinline__ unsigned short f2bf(float x) {
    unsigned u = __float_as_uint(x);
    u += 0x7fffu + ((u >> 16) & 1u);
    return (unsigned short)(u >> 16);
}
__device__ __forceinline__ float bflo(unsigned u) { return __uint_as_float(u << 16); }
__device__ __forceinline__ float bfhi(unsigned u) { return __uint_as_float(u & 0xffff0000u); }
__device__ __forceinline__ unsigned pack2(float a, float b) {
    return (unsigned)f2bf(a) | ((unsigned)f2bf(b) << 16);
}
__device__ __forceinline__ float dot8(uint4 a, uint4 b) {
    return bflo(a.x) * bflo(b.x) + bfhi(a.x) * bfhi(b.x)
         + bflo(a.y) * bflo(b.y) + bfhi(a.y) * bfhi(b.y)
         + bflo(a.z) * bflo(b.z) + bfhi(a.z) * bfhi(b.z)
         + bflo(a.w) * bflo(b.w) + bfhi(a.w) * bfhi(b.w);
}

__global__ void zero_kernel(int* deg, int* cursor, int* tcnt, int* tcur, int N) {
    int i = blockIdx.x * blockDim.x + threadIdx.x;
    int stride = gridDim.x * blockDim.x;
    if (i < 4) { tcnt[i] = 0; tcur[i] = 0; }
    for (int j = i; j < N; j += stride) { deg[j] = 0; cursor[j] = 0; }
}

__global__ void count_types(const int* __restrict__ ntype, int* __restrict__ tcnt, int N) {
    int i = blockIdx.x * 256 + threadIdx.x;
    if (i >= N) return;
    int t = ntype[i];
    int l = threadIdx.x & 63;
    #pragma unroll
    for (int tt = 0; tt < 4; ++tt) {
        unsigned long long mask = __ballot(t == tt);
        if (t == tt) {
            int rank = __popcll(mask & ((1ull << l) - 1ull));
            if (rank == 0) atomicAdd(&tcnt[tt], (int)__popcll(mask));
        }
    }
}

__global__ void base_kernel(const int* __restrict__ tcnt, int* __restrict__ tbase) {
    if (threadIdx.x == 0) {
        int s = 0;
        for (int t = 0; t < 4; ++t) { tbase[t] = s; s += tcnt[t]; }
    }
}

__global__ void place_nodes(const int* __restrict__ ntype, const int* __restrict__ tbase,
                            int* __restrict__ tcur, int* __restrict__ nlist,
                            int* __restrict__ spos, int* __restrict__ stype_s, int N) {
    int i = blockIdx.x * 256 + threadIdx.x;
    if (i >= N) return;
    int t = ntype[i];
    int l = threadIdx.x & 63;
    #pragma unroll
    for (int tt = 0; tt < 4; ++tt) {
        unsigned long long mask = __ballot(t == tt);
        if (t == tt) {
            int rank = __popcll(mask & ((1ull << l) - 1ull));
            int base = 0;
            if (rank == 0) base = atomicAdd(&tcur[tt], (int)__popcll(mask));
            int leader = (int)(__ffsll((unsigned long long)mask) - 1);
            base = __shfl(base, leader);
            int p = tbase[tt] + base + rank;
            nlist[p] = i;
            spos[i] = p;
            stype_s[p] = t;
        }
    }
}

__global__ void deg_kernel(const int* __restrict__ ei, int* __restrict__ deg, int E) {
    int i = blockIdx.x * blockDim.x + threadIdx.x;
    int stride = gridDim.x * blockDim.x;
    for (int e = i; e < E; e += stride) atomicAdd(&deg[ei[E + e]], 1);
}

__global__ __launch_bounds__(256) void scanA(const int* __restrict__ deg, int* __restrict__ excl,
                                             int* __restrict__ bsum, int N) {
    __shared__ int tmp[256];
    int i = blockIdx.x * 256 + threadIdx.x;
    int v = i < N ? deg[i] : 0;
    tmp[threadIdx.x] = v;
    __syncthreads();
    #pragma unroll
    for (int off = 1; off < 256; off <<= 1) {
        int t = threadIdx.x >= off ? tmp[threadIdx.x - off] : 0;
        __syncthreads();
        tmp[threadIdx.x] += t;
        __syncthreads();
    }
    if (i < N) excl[i] = tmp[threadIdx.x] - v;
    if (threadIdx.x == 255) bsum[blockIdx.x] = tmp[255];
}

__global__ __launch_bounds__(256) void scanB(int* __restrict__ bsum, int nb) {
    __shared__ int tmp[256];
    int v = threadIdx.x < nb ? bsum[threadIdx.x] : 0;
    tmp[threadIdx.x] = v;
    __syncthreads();
    #pragma unroll
    for (int off = 1; off < 256; off <<= 1) {
        int t = threadIdx.x >= off ? tmp[threadIdx.x - off] : 0;
        __syncthreads();
        tmp[threadIdx.x] += t;
        __syncthreads();
    }
    if (threadIdx.x < nb) bsum[threadIdx.x] = tmp[threadIdx.x] - v;
}

__global__ void scanC(const int* __restrict__ excl, const int* __restrict__ bsum,
                      int* __restrict__ row_start, int N) {
    int i = blockIdx.x * blockDim.x + threadIdx.x;
    if (i < N) row_start[i] = excl[i] + bsum[i >> 8];
}

__global__ void scatter_kernel(const int* __restrict__ ei, const int* __restrict__ etype,
                               const int* __restrict__ etime, const int* __restrict__ ntype,
                               const int* __restrict__ row_start, int* __restrict__ cursor,
                               const int* __restrict__ spos, int2* __restrict__ ebuf, int E) {
    int i = blockIdx.x * blockDim.x + threadIdx.x;
    int stride = gridDim.x * blockDim.x;
    for (int e = i; e < E; e += stride) {
        int src = ei[e], tgt = ei[E + e];
        int pos = atomicAdd(&cursor[tgt], 1);
        int2 v;
        v.x = spos[src];
        v.y = etype[e] | (etime[e] << 2) | (ntype[src] << 10);
        ebuf[row_start[tgt] + pos] = v;
    }
}

// rte_out[m,d] = (sinusoid emb row m) @ rte_W + rte_b   [240,128] f32
__global__ __launch_bounds__(128) void rte_out_kernel(const float* __restrict__ rte_W,
                                                      const float* __restrict__ rte_b,
                                                      float* __restrict__ rte_out) {
    int m = blockIdx.x, d = threadIdx.x;
    __shared__ float emb[128];
    int j2 = d & ~1;
    float div = expf((float)j2 * (-9.210340371976184f / 128.f));
    float ang = (float)m * div;
    float val = ((d & 1) ? cosf(ang) : sinf(ang)) * 0.08838834764831845f;
    emb[d] = val;
    __syncthreads();
    float acc = rte_b[d];
    #pragma unroll 8
    for (int i = 0; i < 128; ++i) acc += emb[i] * rte_W[i * 128 + d];
    rte_out[m * 128 + d] = acc;
}

// krte_bf[t,m,:] = rte_out[m] @ Wk_t (bf16); vmrte_bf[t,r,m,:] = (rte_out[m] @ Wv_t)^T M_r
__global__ __launch_bounds__(128) void rte_tables(
    const float* __restrict__ rte_out, const float* __restrict__ Wk,
    const float* __restrict__ Wv, const float* __restrict__ rel_msg,
    unsigned short* __restrict__ krte_bf, unsigned short* __restrict__ vmrte_bf) {
    int m = blockIdx.x, t = blockIdx.y, d = threadIdx.x;
    __shared__ float sr[128];
    __shared__ float vr[128];
    sr[d] = rte_out[m * 128 + d];
    __syncthreads();
    float ak = 0.f, av = 0.f;
    for (int i = 0; i < 128; ++i) {
        float rv = sr[i];
        ak += rv * Wk[(t * 128 + i) * 128 + d];
        av += rv * Wv[(t * 128 + i) * 128 + d];
    }
    krte_bf[(size_t)(t * MAXLEN + m) * 128 + d] = f2bf(ak);
    vr[d] = av;
    __syncthreads();
    int h = d >> 4, dd = d & 15;
    for (int r = 0; r < NR; ++r) {
        float acc = 0.f;
        #pragma unroll
        for (int k = 0; k < 16; ++k)
            acc += vr[h * 16 + k] * rel_msg[((r * NH + h) * 16 + k) * 16 + dd];
        vmrte_bf[(size_t)((t * 4 + r) * MAXLEN + m) * 128 + d] = f2bf(acc);
    }
}

// Pack Wk/Wq/Wv/Wa into MFMA B-fragment order, bf16.
__global__ __launch_bounds__(256) void pack_w(
    const float* __restrict__ Wk, const float* __restrict__ Wq,
    const float* __restrict__ Wv, const float* __restrict__ Wa,
    short* __restrict__ PW) {
    int idx = blockIdx.x * 256 + threadIdx.x;  // 32768 total
    int lane = idx & 63;
    int ks = (idx >> 6) & 3;
    int ctg = (idx >> 8) & 7;
    int t = (idx >> 11) & 3;
    int set = idx >> 13;
    const float* W = set == 0 ? Wk : set == 1 ? Wq : set == 2 ? Wv : Wa;
    const float* Wt = W + t * 16384;
    int col = ctg * 16 + (lane & 15);
    int k0 = ks * 32 + (lane >> 4) * 8;
    unsigned short o[8];
    #pragma unroll
    for (int j = 0; j < 8; ++j) o[j] = f2bf(Wt[(k0 + j) * 128 + col]);
    uint4 pk;
    pk.x = (unsigned)o[0] | ((unsigned)o[1] << 16);
    pk.y = (unsigned)o[2] | ((unsigned)o[3] << 16);
    pk.z = (unsigned)o[4] | ((unsigned)o[5] << 16);
    pk.w = (unsigned)o[6] | ((unsigned)o[7] << 16);
    *reinterpret_cast<uint4*>(PW + (size_t)idx * 8) = pk;
}

// Apk[r][h][kk][dp] = rel_att[r,h,kk,dp]*pri[r,h]/4 (bf16);  Mtp[r][h][kk][kp] = rel_msg[r,h,kp,kk]
__global__ void pack_abm(const float* __restrict__ rel_att, const float* __restrict__ rel_msg,
                         const float* __restrict__ rel_pri,
                         unsigned short* __restrict__ Apk, unsigned short* __restrict__ Mtp) {
    int idx = blockIdx.x * 256 + threadIdx.x;  // 8192
    int dp = idx & 15, kk = (idx >> 4) & 15, h = (idx >> 8) & 7, r = idx >> 11;
    float a = rel_att[(((r * 8 + h) * 16 + kk) * 16) + dp] * rel_pri[r * 8 + h] * 0.25f;
    Apk[idx] = f2bf(a);
    float mm = rel_msg[(((r * 8 + h) * 16 + dp) * 16) + kk];
    Mtp[idx] = f2bf(mm);
}

// 32 sorted nodes/tile: MFMA K/Q/V (types t0..t1 only), LDS-staged outputs,
// coalesced kn store, in-LDS qa/vm tail with bf16 reg tables.
__global__ __launch_bounds__(256, 4) void kqv_sorted(
    const float* __restrict__ x, const int* __restrict__ nlist_,
    const int* __restrict__ stype_s, const short* __restrict__ PW,
    const float* __restrict__ bk, const float* __restrict__ bq, const float* __restrict__ bv,
    const unsigned short* __restrict__ Apk, const unsigned short* __restrict__ Mtp,
    unsigned short* __restrict__ kn_s, unsigned short* __restrict__ qa_s,
    unsigned short* __restrict__ vm_s, int N) {
    __shared__ short af_l[2][4][64][8];        // A fragments, 8 KB
    __shared__ unsigned short kb[32][128];     // 8 KB each
    __shared__ unsigned short qb[32][128];
    __shared__ unsigned short vb[32][128];
    __shared__ int st_l[32];
    const int tid = threadIdx.x;
    const int sp0 = blockIdx.x * 32;

    if (tid < 32) {
        int sp = sp0 + tid;
        st_l[tid] = stype_s[sp < N ? sp : N - 1];
    }
    {
        int i = tid >> 3;            // row 0..31
        int d0 = (tid & 7) * 16;     // 0..112
        int sp = sp0 + i;
        int nid = nlist_[sp < N ? sp : N - 1];
        const float* xr = x + (size_t)nid * 128 + d0;
        float4 f0 = *reinterpret_cast<const float4*>(xr);
        float4 f1 = *reinterpret_cast<const float4*>(xr + 4);
        float4 f2 = *reinterpret_cast<const float4*>(xr + 8);
        float4 f3 = *reinterpret_cast<const float4*>(xr + 12);
        int m = i >> 4, rr = i & 15;
        int ks = d0 >> 5;
        int sub = (d0 >> 3) & 3;
        uint4 p0, p1;
        p0.x = pack2(f0.x, f0.y); p0.y = pack2(f0.z, f0.w);
        p0.z = pack2(f1.x, f1.y); p0.w = pack2(f1.z, f1.w);
        p1.x = pack2(f2.x, f2.y); p1.y = pack2(f2.z, f2.w);
        p1.z = pack2(f3.x, f3.y); p1.w = pack2(f3.z, f3.w);
        *reinterpret_cast<uint4*>(&af_l[m][ks][sub * 16 + rr][0]) = p0;
        *reinterpret_cast<uint4*>(&af_l[m][ks][(sub + 1) * 16 + rr][0]) = p1;
    }
    __syncthreads();

    const int lane = tid & 63, w = tid >> 6;
    const int col_l = lane & 15, rowg = lane >> 4;
    const int t0 = st_l[0], t1 = st_l[31];

    bf16x8 afr[2][4];
    #pragma unroll
    for (int m = 0; m < 2; ++m)
        #pragma unroll
        for (int ks = 0; ks < 4; ++ks)
            afr[m][ks] = *reinterpret_cast<const bf16x8*>(&af_l[m][ks][lane][0]);

    for (int set = 0; set < 3; ++set) {
        const float* bias = set == 0 ? bk : (set == 1 ? bq : bv);
        unsigned short* sb = set == 0 ? &kb[0][0] : (set == 1 ? &qb[0][0] : &vb[0][0]);
        for (int t = t0; t <= t1; ++t) {
            #pragma unroll
            for (int c = 0; c < 2; ++c) {
                int ctg = w + c * 4;
                bf16x8 pf[4];
                #pragma unroll
                for (int ks = 0; ks < 4; ++ks)
                    pf[ks] = *reinterpret_cast<const bf16x8*>(
                        PW + ((size_t)((((set * 4 + t) * 8 + ctg) * 4 + ks) * 64 + lane)) * 8);
                float bval = bias[t * 128 + ctg * 16 + col_l];
                #pragma unroll
                for (int m = 0; m < 2; ++m) {
                    f32x4 acc = {0.f, 0.f, 0.f, 0.f};
                    #pragma unroll
                    for (int ks = 0; ks < 4; ++ks)
                        acc = __builtin_amdgcn_mfma_f32_16x16x32_bf16(afr[m][ks], pf[ks], acc, 0, 0, 0);
                    #pragma unroll
                    for (int j = 0; j < 4; ++j) {
                        int i = m * 16 + rowg * 4 + j;
                        if (st_l[i] == t)
                            sb[i * 128 + ctg * 16 + col_l] = f2bf(acc[j] + bval);
                    }
                }
            }
        }
    }
    __syncthreads();

    // coalesced kn store
    {
        int i = tid >> 3, d0 = (tid & 7) * 16;
        if (sp0 + i < N) {
            uint4 v0 = *reinterpret_cast<const uint4*>(&kb[i][d0]);
            uint4 v1 = *reinterpret_cast<const uint4*>(&kb[i][d0 + 8]);
            unsigned short* dst = kn_s + (size_t)(sp0 + i) * 128 + d0;
            *reinterpret_cast<uint4*>(dst) = v0;
            *reinterpret_cast<uint4*>(dst + 8) = v1;
        }
    }

    // qa/vm tail: hk = (h,kk); half handles 16 nodes
    const int hk = tid & 127, half = tid >> 7;
    const int h = hk >> 4, kk = hk & 15;
    for (int r = 0; r < NR; ++r) {
        int tb = ((r * 8 + h) * 16 + kk) * 16;
        uint4 a0 = *reinterpret_cast<const uint4*>(Apk + tb);
        uint4 a1 = *reinterpret_cast<const uint4*>(Apk + tb + 8);
        uint4 m0 = *reinterpret_cast<const uint4*>(Mtp + tb);
        uint4 m1 = *reinterpret_cast<const uint4*>(Mtp + tb + 8);
        for (int n = 0; n < 16; ++n) {
            int i = half * 16 + n;
            int sp = sp0 + i;
            uint4 ql = *reinterpret_cast<const uint4*>(&qb[i][h * 16]);
            uint4 qh2 = *reinterpret_cast<const uint4*>(&qb[i][h * 16 + 8]);
            uint4 vl = *reinterpret_cast<const uint4*>(&vb[i][h * 16]);
            uint4 vh2 = *reinterpret_cast<const uint4*>(&vb[i][h * 16 + 8]);
            float qa = dot8(a0, ql) + dot8(a1, qh2);
            float vm = dot8(m0, vl) + dot8(m1, vh2);
            if (sp < N) {
                qa_s[((size_t)sp * 4 + r) * 128 + hk] = f2bf(qa);
                vm_s[((size_t)sp * 4 + r) * 128 + hk] = f2bf(vm);
            }
        }
    }
}

// One sorted node per 16 lanes. CSR edges; online softmax per head; no atomics.
__global__ __launch_bounds__(256) void fused_edge_attn(
    const int2* __restrict__ ebuf, const int* __restrict__ row_start, const int* __restrict__ deg,
    const int* __restrict__ nlist_,
    const unsigned short* __restrict__ kn_s, const unsigned short* __restrict__ krte_bf,
    const unsigned short* __restrict__ qa_s, const unsigned short* __restrict__ vm_s,
    const unsigned short* __restrict__ vmrte_bf,
    float* __restrict__ aggr, int N) {
    int sp = blockIdx.x * 16 + (threadIdx.x >> 4);
    int l16 = threadIdx.x & 15;
    if (sp >= N) return;
    int node = nlist_[sp];
    uint4 q[4];
    #pragma unroll
    for (int r = 0; r < 4; ++r)
        q[r] = *reinterpret_cast<const uint4*>(qa_s + ((size_t)sp * 4 + r) * 128 + l16 * 8);
    int start = row_start[node], cnt = deg[node];
    float m = -INFINITY, den = 0.f;
    float acc[8] = {0.f, 0.f, 0.f, 0.f, 0.f, 0.f, 0.f, 0.f};
    for (int i = 0; i < cnt; ++i) {
        int2 em = ebuf[start + i];
        int sps = em.x;
        int r = em.y & 3, tm = (em.y >> 2) & 255, st = (em.y >> 10) & 3;
        uint4 kv = *reinterpret_cast<const uint4*>(kn_s + (size_t)sps * 128 + l16 * 8);
        uint4 kr = *reinterpret_cast<const uint4*>(krte_bf + (size_t)(st * MAXLEN + tm) * 128 + l16 * 8);
        uint4 qr = q[r];
        float p = 0.f;
        p += (bflo(kv.x) + bflo(kr.x)) * bflo(qr.x);
        p += (bfhi(kv.x) + bfhi(kr.x)) * bfhi(qr.x);
        p += (bflo(kv.y) + bflo(kr.y)) * bflo(qr.y);
        p += (bfhi(kv.y) + bfhi(kr.y)) * bfhi(qr.y);
        p += (bflo(kv.z) + bflo(kr.z)) * bflo(qr.z);
        p += (bfhi(kv.z) + bfhi(kr.z)) * bfhi(qr.z);
        p += (bflo(kv.w) + bflo(kr.w)) * bflo(qr.w);
        p += (bfhi(kv.w) + bfhi(kr.w)) * bfhi(qr.w);
        p += __shfl_xor(p, 1);
        uint4 mv = *reinterpret_cast<const uint4*>(vm_s + ((size_t)sps * 4 + r) * 128 + l16 * 8);
        uint4 mr = *reinterpret_cast<const uint4*>(vmrte_bf + (size_t)((st * 4 + r) * MAXLEN + tm) * 128 + l16 * 8);
        float mnew = fmaxf(m, p);
        float s = __expf(m - mnew);
        float wgt = __expf(p - mnew);
        den = den * s + wgt;
        acc[0] = acc[0] * s + wgt * (bflo(mv.x) + bflo(mr.x));
        acc[1] = acc[1] * s + wgt * (bfhi(mv.x) + bfhi(mr.x));
        acc[2] = acc[2] * s + wgt * (bflo(mv.y) + bflo(mr.y));
        acc[3] = acc[3] * s + wgt * (bfhi(mv.y) + bfhi(mr.y));
        acc[4] = acc[4] * s + wgt * (bflo(mv.z) + bflo(mr.z));
        acc[5] = acc[5] * s + wgt * (bfhi(mv.z) + bfhi(mr.z));
        acc[6] = acc[6] * s + wgt * (bflo(mv.w) + bflo(mr.w));
        acc[7] = acc[7] * s + wgt * (bfhi(mv.w) + bfhi(mr.w));
        m = mnew;
    }
    float inv = den > 0.f ? 1.f / den : 0.f;
    float4 o0, o1;
    o0.x = acc[0] * inv; o0.y = acc[1] * inv; o0.z = acc[2] * inv; o0.w = acc[3] * inv;
    o1.x = acc[4] * inv; o1.y = acc[5] * inv; o1.z = acc[6] * inv; o1.w = acc[7] * inv;
    float* ap = aggr + (size_t)node * 128 + l16 * 8;
    *reinterpret_cast<float4*>(ap) = o0;
    *reinterpret_cast<float4*>(ap + 4) = o1;
}

// 16 nodes/block: gelu(aggr) -> bf16 -> MFMA vs Wa (all types, select) -> skip-blend -> LN
__global__ __launch_bounds__(256) void node_update_mfma(
    const float* __restrict__ x, const int* __restrict__ ntype,
    const float* __restrict__ aggr, const short* __restrict__ PW,
    const float* __restrict__ ba, const float* __restrict__ gamma,
    const float* __restrict__ beta, const float* __restrict__ skip,
    float* __restrict__ out) {
    __shared__ short xs2[2048];
    __shared__ float hs[16][128];
    const int tid = threadIdx.x;
    const int nb = blockIdx.x;
    #pragma unroll
    for (int s = 0; s < 8; ++s) {
        int flat = tid + s * 256;
        int ni = flat >> 7, d = flat & 127;
        float v = aggr[((size_t)nb * 16 + ni) * 128 + d];
        float g = 0.5f * v * (1.f + erff(v * 0.7071067811865476f));
        xs2[((d >> 3) * 16 + ni) * 8 + (d & 7)] = (short)f2bf(g);
    }
    __syncthreads();
    const int lane = tid & 63, w = tid >> 6;
    bf16x8 af[4];
    #pragma unroll
    for (int ks = 0; ks < 4; ++ks)
        af[ks] = *reinterpret_cast<const bf16x8*>(&xs2[((ks * 4 + (lane >> 4)) * 16 + (lane & 15)) * 8]);
    const int row0 = (lane >> 4) * 4;
    int types[4];
    #pragma unroll
    for (int j = 0; j < 4; ++j) types[j] = ntype[nb * 16 + row0 + j];

    for (int t = 0; t < NT; ++t) {
        float alpha = 1.f / (1.f + expf(-skip[t]));
        #pragma unroll
        for (int ctl = 0; ctl < 2; ++ctl) {
            int ctg = w * 2 + ctl;
            f32x4 acc = {0.f, 0.f, 0.f, 0.f};
            #pragma unroll
            for (int ks = 0; ks < 4; ++ks) {
                bf16x8 bfrag = *reinterpret_cast<const bf16x8*>(
                    PW + ((size_t)((((3 * 4 + t) * 8 + ctg) * 4 + ks) * 64 + lane)) * 8);
                acc = __builtin_amdgcn_mfma_f32_16x16x32_bf16(af[ks], bfrag, acc, 0, 0, 0);
            }
            int col = ctg * 16 + (lane & 15);
            float bval = ba[t * 128 + col];
            #pragma unroll
            for (int j = 0; j < 4; ++j) {
                if (types[j] == t) {
                    int rowj = row0 + j;
                    float tr = acc[j] + bval;
                    float xv = x[((size_t)nb * 16 + rowj) * 128 + col];
                    hs[rowj][col] = tr * alpha + xv * (1.f - alpha);
                }
            }
        }
    }
    __syncthreads();
    const int node = tid >> 4, l16 = tid & 15;
    float s1 = 0.f, s2 = 0.f;
    float hv[8];
    #pragma unroll
    for (int j = 0; j < 8; ++j) {
        hv[j] = hs[node][l16 * 8 + j];
        s1 += hv[j];
        s2 += hv[j] * hv[j];
    }
    #pragma unroll
    for (int off = 1; off < 16; off <<= 1) {
        s1 += __shfl_xor(s1, off);
        s2 += __shfl_xor(s2, off);
    }
    float mu = s1 * (1.f / 128.f);
    float var = s2 * (1.f / 128.f) - mu * mu;
    float inv = 1.f / sqrtf(var + 1e-5f);
    int t = ntype[nb * 16 + node];
    #pragma unroll
    for (int j = 0; j < 8; ++j) {
        int d = l16 * 8 + j;
        out[((size_t)nb * 16 + node) * 128 + d] = (hv[j] - mu) * inv * gamma[t * 128 + d] + beta[t * 128 + d];
    }
}

extern "C" void kernel_launch(void* const* d_in, const int* in_sizes, int n_in,
                              void* d_out, int out_size, void* d_ws, size_t ws_size,
                              hipStream_t stream) {
    const float* node_inp = (const float*)d_in[0];
    const int*   node_type = (const int*)d_in[1];
    const int*   edge_index = (const int*)d_in[2];
    const int*   edge_type = (const int*)d_in[3];
    const int*   edge_time = (const int*)d_in[4];
    const float* Wk = (const float*)d_in[5];
    const float* bk = (const float*)d_in[6];
    const float* Wq = (const float*)d_in[7];
    const float* bq = (const float*)d_in[8];
    const float* Wv = (const float*)d_in[9];
    const float* bv = (const float*)d_in[10];
    const float* Wa = (const float*)d_in[11];
    const float* ba = (const float*)d_in[12];
    const float* gamma = (const float*)d_in[13];
    const float* beta = (const float*)d_in[14];
    const float* rel_pri = (const float*)d_in[15];
    const float* rel_att = (const float*)d_in[16];
    const float* rel_msg = (const float*)d_in[17];
    const float* skip = (const float*)d_in[18];
    const float* rte_W = (const float*)d_in[19];
    const float* rte_b = (const float*)d_in[20];

    int N = in_sizes[0] / 128;   // 50000
    int E = in_sizes[3];         // 600000

    char* base = (char*)d_ws;
    float* aggr = (float*)base;               base += (size_t)N * 128 * 4;
    float* rte_out = (float*)base;            base += (size_t)MAXLEN * 128 * 4;
    unsigned short* kn_s = (unsigned short*)base;     base += (size_t)N * 128 * 2;
    unsigned short* qa_s = (unsigned short*)base;     base += (size_t)N * 4 * 128 * 2;
    unsigned short* vm_s = (unsigned short*)base;     base += (size_t)N * 4 * 128 * 2;
    unsigned short* krte_bf = (unsigned short*)base;  base += (size_t)NT * MAXLEN * 128 * 2;
    unsigned short* vmrte_bf = (unsigned short*)base; base += (size_t)NT * NR * MAXLEN * 128 * 2;
    short* PW = (short*)base;                 base += (size_t)4 * NT * 128 * 128 * 2;
    unsigned short* Apk = (unsigned short*)base;      base += 8192 * 2;
    unsigned short* Mtp = (unsigned short*)base;      base += 8192 * 2;
    int* deg = (int*)base;                    base += (size_t)N * 4;
    int* cursor = (int*)base;                 base += (size_t)N * 4;
    int* excl = (int*)base;                   base += (size_t)N * 4;
    int* row_start = (int*)base;              base += (size_t)N * 4;
    int* nlist = (int*)base;                  base += (size_t)N * 4;
    int* spos = (int*)base;                   base += (size_t)N * 4;
    int* stype_s = (int*)base;                base += (size_t)N * 4;
    int* bsum = (int*)base;                   base += 256 * 4;
    int* tcnt = (int*)base;                   base += 4 * 4;
    int* tcur = (int*)base;                   base += 4 * 4;
    int* tbase = (int*)base;                  base += 4 * 4;
    base = (char*)(((size_t)base + 15) & ~(size_t)15);
    int2* ebuf = (int2*)base;                 base += (size_t)E * 8;

    int nb = (N + 255) / 256;   // 196
    int ng = (N + 255) / 256;

    zero_kernel<<<256, 256, 0, stream>>>(deg, cursor, tcnt, tcur, N);
    count_types<<<ng, 256, 0, stream>>>(node_type, tcnt, N);
    base_kernel<<<1, 64, 0, stream>>>(tcnt, tbase);
    place_nodes<<<ng, 256, 0, stream>>>(node_type, tbase, tcur, nlist, spos, stype_s, N);
    deg_kernel<<<1024, 256, 0, stream>>>(edge_index, deg, E);
    scanA<<<nb, 256, 0, stream>>>(deg, excl, bsum, N);
    scanB<<<1, 256, 0, stream>>>(bsum, nb);
    scanC<<<nb, 256, 0, stream>>>(excl, bsum, row_start, N);
    scatter_kernel<<<1024, 256, 0, stream>>>(edge_index, edge_type, edge_time, node_type,
                                             row_start, cursor, spos, ebuf, E);
    rte_out_kernel<<<MAXLEN, 128, 0, stream>>>(rte_W, rte_b, rte_out);
    dim3 gt(MAXLEN, NT);
    rte_tables<<<gt, 128, 0, stream>>>(rte_out, Wk, Wv, rel_msg, krte_bf, vmrte_bf);
    pack_w<<<128, 256, 0, stream>>>(Wk, Wq, Wv, Wa, PW);
    pack_abm<<<32, 256, 0, stream>>>(rel_att, rel_msg, rel_pri, Apk, Mtp);
    kqv_sorted<<<(N + 31) / 32, 256, 0, stream>>>(node_inp, nlist, stype_s, PW, bk, bq, bv,
                                                  Apk, Mtp, kn_s, qa_s, vm_s, N);
    fused_edge_attn<<<(N + 15) / 16, 256, 0, stream>>>(ebuf, row_start, deg, nlist,
                                                       kn_s, krte_bf, qa_s, vm_s, vmrte_bf,
                                                       aggr, N);
    node_update_mfma<<<N / 16, 256, 0, stream>>>(node_inp, node_type, aggr, PW, ba,
                                                 gamma, beta, skip, (float*)d_out);
}

// Round 5
// 332.580 us; speedup vs baseline: 8.3538x; 1.1071x over previous
//
#include <hip/hip_runtime.h>
#include <math.h>

#define NH 8
#define NT 4
#define NR 4
#define MAXLEN 240

typedef __attribute__((ext_vector_type(8))) short bf16x8;
typedef __attribute__((ext_vector_type(4))) float f32x4;

__device__ __forceinline__ unsigned short f2bf(float x) {
    unsigned u = __float_as_uint(x);
    u += 0x7fffu + ((u >> 16) & 1u);
    return (unsigned short)(u >> 16);
}
__device__ __forceinline__ float bflo(unsigned u) { return __uint_as_float(u << 16); }
__device__ __forceinline__ float bfhi(unsigned u) { return __uint_as_float(u & 0xffff0000u); }
__device__ __forceinline__ unsigned pack2(float a, float b) {
    return (unsigned)f2bf(a) | ((unsigned)f2bf(b) << 16);
}

__global__ void zero_kernel(int* deg, int* cursor, int* tcnt, int* tcur, int N) {
    int i = blockIdx.x * blockDim.x + threadIdx.x;
    int stride = gridDim.x * blockDim.x;
    if (i < 4) { tcnt[i] = 0; tcur[i] = 0; }
    for (int j = i; j < N; j += stride) { deg[j] = 0; cursor[j] = 0; }
}

__global__ void count_types(const int* __restrict__ ntype, int* __restrict__ tcnt, int N) {
    int i = blockIdx.x * 256 + threadIdx.x;
    if (i >= N) return;
    int t = ntype[i];
    int l = threadIdx.x & 63;
    #pragma unroll
    for (int tt = 0; tt < 4; ++tt) {
        unsigned long long mask = __ballot(t == tt);
        if (t == tt) {
            int rank = __popcll(mask & ((1ull << l) - 1ull));
            if (rank == 0) atomicAdd(&tcnt[tt], (int)__popcll(mask));
        }
    }
}

__global__ void base_kernel(const int* __restrict__ tcnt, int* __restrict__ tbase) {
    if (threadIdx.x == 0) {
        int s = 0;
        for (int t = 0; t < 4; ++t) { tbase[t] = s; s += tcnt[t]; }
    }
}

__global__ void place_nodes(const int* __restrict__ ntype, const int* __restrict__ tbase,
                            int* __restrict__ tcur, int* __restrict__ nlist,
                            int* __restrict__ spos, int* __restrict__ stype_s, int N) {
    int i = blockIdx.x * 256 + threadIdx.x;
    if (i >= N) return;
    int t = ntype[i];
    int l = threadIdx.x & 63;
    #pragma unroll
    for (int tt = 0; tt < 4; ++tt) {
        unsigned long long mask = __ballot(t == tt);
        if (t == tt) {
            int rank = __popcll(mask & ((1ull << l) - 1ull));
            int base = 0;
            if (rank == 0) base = atomicAdd(&tcur[tt], (int)__popcll(mask));
            int leader = (int)(__ffsll((unsigned long long)mask) - 1);
            base = __shfl(base, leader);
            int p = tbase[tt] + base + rank;
            nlist[p] = i;
            spos[i] = p;
            stype_s[p] = t;
        }
    }
}

// degree counted in SORTED index space
__global__ void deg_kernel(const int* __restrict__ ei, const int* __restrict__ spos,
                           int* __restrict__ deg, int E) {
    int i = blockIdx.x * blockDim.x + threadIdx.x;
    int stride = gridDim.x * blockDim.x;
    for (int e = i; e < E; e += stride) atomicAdd(&deg[spos[ei[E + e]]], 1);
}

__global__ __launch_bounds__(256) void scanA(const int* __restrict__ deg, int* __restrict__ excl,
                                             int* __restrict__ bsum, int N) {
    __shared__ int tmp[256];
    int i = blockIdx.x * 256 + threadIdx.x;
    int v = i < N ? deg[i] : 0;
    tmp[threadIdx.x] = v;
    __syncthreads();
    #pragma unroll
    for (int off = 1; off < 256; off <<= 1) {
        int t = threadIdx.x >= off ? tmp[threadIdx.x - off] : 0;
        __syncthreads();
        tmp[threadIdx.x] += t;
        __syncthreads();
    }
    if (i < N) excl[i] = tmp[threadIdx.x] - v;
    if (threadIdx.x == 255) bsum[blockIdx.x] = tmp[255];
}

__global__ __launch_bounds__(256) void scanB(int* __restrict__ bsum, int nb) {
    __shared__ int tmp[256];
    int v = threadIdx.x < nb ? bsum[threadIdx.x] : 0;
    tmp[threadIdx.x] = v;
    __syncthreads();
    #pragma unroll
    for (int off = 1; off < 256; off <<= 1) {
        int t = threadIdx.x >= off ? tmp[threadIdx.x - off] : 0;
        __syncthreads();
        tmp[threadIdx.x] += t;
        __syncthreads();
    }
    if (threadIdx.x < nb) bsum[threadIdx.x] = tmp[threadIdx.x] - v;
}

__global__ void scanC(const int* __restrict__ excl, const int* __restrict__ bsum,
                      int* __restrict__ row_start, int N) {
    int i = blockIdx.x * blockDim.x + threadIdx.x;
    if (i < N) row_start[i] = excl[i] + bsum[i >> 8];
}

__global__ void scatter_kernel(const int* __restrict__ ei, const int* __restrict__ etype,
                               const int* __restrict__ etime, const int* __restrict__ spos,
                               const int* __restrict__ tbase,
                               const int* __restrict__ row_start, int* __restrict__ cursor,
                               int2* __restrict__ ebuf, int E) {
    int tb1 = tbase[1], tb2 = tbase[2], tb3 = tbase[3];
    int i = blockIdx.x * blockDim.x + threadIdx.x;
    int stride = gridDim.x * blockDim.x;
    for (int e = i; e < E; e += stride) {
        int sps = spos[ei[e]];
        int spt = spos[ei[E + e]];
        int st = (sps >= tb1) + (sps >= tb2) + (sps >= tb3);
        int pos = atomicAdd(&cursor[spt], 1);
        int2 v;
        v.x = sps;
        v.y = etype[e] | (etime[e] << 2) | (st << 10);
        ebuf[row_start[spt] + pos] = v;
    }
}

// Fused RTE: compute sinusoid row m, project through rte_W (+b), then through
// Wk_t -> krte ; through Wv_t then M_r -> vmrte.  grid (240, 4)
__global__ __launch_bounds__(128) void rte_tables(
    const float* __restrict__ rte_W, const float* __restrict__ rte_b,
    const float* __restrict__ Wk, const float* __restrict__ Wv,
    const float* __restrict__ rel_msg,
    unsigned short* __restrict__ krte_bf, unsigned short* __restrict__ vmrte_bf) {
    int m = blockIdx.x, t = blockIdx.y, d = threadIdx.x;
    __shared__ float emb[128];
    __shared__ float sr[128];
    __shared__ float vr[128];
    int j2 = d & ~1;
    float div = expf((float)j2 * (-9.210340371976184f / 128.f));
    float ang = (float)m * div;
    emb[d] = ((d & 1) ? cosf(ang) : sinf(ang)) * 0.08838834764831845f;
    __syncthreads();
    float ro = rte_b[d];
    #pragma unroll 8
    for (int i = 0; i < 128; ++i) ro += emb[i] * rte_W[i * 128 + d];
    sr[d] = ro;
    __syncthreads();
    float ak = 0.f, av = 0.f;
    for (int i = 0; i < 128; ++i) {
        float rv = sr[i];
        ak += rv * Wk[(t * 128 + i) * 128 + d];
        av += rv * Wv[(t * 128 + i) * 128 + d];
    }
    krte_bf[(size_t)(t * MAXLEN + m) * 128 + d] = f2bf(ak);
    vr[d] = av;
    __syncthreads();
    int h = d >> 4, dd = d & 15;
    for (int r = 0; r < NR; ++r) {
        float acc = 0.f;
        #pragma unroll
        for (int k = 0; k < 16; ++k)
            acc += vr[h * 16 + k] * rel_msg[((r * NH + h) * 16 + k) * 16 + dd];
        vmrte_bf[(size_t)((t * 4 + r) * MAXLEN + m) * 128 + d] = f2bf(acc);
    }
}

// Fold rel_att/rel_msg into Wq/Wv and pack 10 weight sets into MFMA B-fragment
// order (bf16): set0=Wk, 1-4=Wqa_r, 5-8=Wvm_r, 9=Wa. Also folded biases (f32).
// PW2[set][t][ctg(8)][ks(4)][lane(64)][j(8)]; elem = Wf[k=ks*32+(lane>>4)*8+j][col=ctg*16+(lane&15)]
__global__ __launch_bounds__(256) void pack_w9(
    const float* __restrict__ Wk, const float* __restrict__ Wq,
    const float* __restrict__ Wv, const float* __restrict__ Wa,
    const float* __restrict__ bk, const float* __restrict__ bq,
    const float* __restrict__ bv, const float* __restrict__ ba,
    const float* __restrict__ rel_att, const float* __restrict__ rel_msg,
    const float* __restrict__ rel_pri,
    short* __restrict__ PW2, float* __restrict__ PB) {
    if (blockIdx.x >= 320) {  // bias blocks: 20 blocks x 256 = 5120 = 10*4*128
        int bidx = (blockIdx.x - 320) * 256 + threadIdx.x;
        int col = bidx & 127, t = (bidx >> 7) & 3, set = bidx >> 9;
        int h = col >> 4, kk = col & 15;
        float val;
        if (set == 0) val = bk[t * 128 + col];
        else if (set == 9) val = ba[t * 128 + col];
        else if (set <= 4) {
            int r = set - 1;
            float pri = rel_pri[r * NH + h] * 0.25f;
            float acc = 0.f;
            #pragma unroll
            for (int dp = 0; dp < 16; ++dp)
                acc += bq[t * 128 + h * 16 + dp] * rel_att[((r * NH + h) * 16 + kk) * 16 + dp];
            val = acc * pri;
        } else {
            int r = set - 5;
            float acc = 0.f;
            #pragma unroll
            for (int kp = 0; kp < 16; ++kp)
                acc += bv[t * 128 + h * 16 + kp] * rel_msg[((r * NH + h) * 16 + kp) * 16 + kk];
            val = acc;
        }
        PB[bidx] = val;
        return;
    }
    int idx = blockIdx.x * 256 + threadIdx.x;  // 81920 = 10*4*2048
    int lane = idx & 63;
    int ks = (idx >> 6) & 3;
    int ctg = (idx >> 8) & 7;
    int t = (idx >> 11) & 3;
    int set = idx >> 13;
    int col = ctg * 16 + (lane & 15);
    int k0 = ks * 32 + (lane >> 4) * 8;
    int h = col >> 4, kk = col & 15;
    unsigned short o[8];
    if (set == 0 || set == 9) {
        const float* W = (set == 0 ? Wk : Wa) + t * 16384;
        #pragma unroll
        for (int j = 0; j < 8; ++j) o[j] = f2bf(W[(k0 + j) * 128 + col]);
    } else if (set <= 4) {
        int r = set - 1;
        float pri = rel_pri[r * NH + h] * 0.25f;
        float Ar[16];
        #pragma unroll
        for (int dp = 0; dp < 16; ++dp)
            Ar[dp] = rel_att[((r * NH + h) * 16 + kk) * 16 + dp] * pri;
        #pragma unroll
        for (int j = 0; j < 8; ++j) {
            const float* wr = Wq + (size_t)(t * 128 + k0 + j) * 128 + h * 16;
            float acc = 0.f;
            #pragma unroll
            for (int dp = 0; dp < 16; ++dp) acc += wr[dp] * Ar[dp];
            o[j] = f2bf(acc);
        }
    } else {
        int r = set - 5;
        float Mc[16];
        #pragma unroll
        for (int kp = 0; kp < 16; ++kp)
            Mc[kp] = rel_msg[((r * NH + h) * 16 + kp) * 16 + kk];
        #pragma unroll
        for (int j = 0; j < 8; ++j) {
            const float* wr = Wv + (size_t)(t * 128 + k0 + j) * 128 + h * 16;
            float acc = 0.f;
            #pragma unroll
            for (int kp = 0; kp < 16; ++kp) acc += wr[kp] * Mc[kp];
            o[j] = f2bf(acc);
        }
    }
    uint4 pk;
    pk.x = (unsigned)o[0] | ((unsigned)o[1] << 16);
    pk.y = (unsigned)o[2] | ((unsigned)o[3] << 16);
    pk.z = (unsigned)o[4] | ((unsigned)o[5] << 16);
    pk.w = (unsigned)o[6] | ((unsigned)o[7] << 16);
    *reinterpret_cast<uint4*>(PW2 + (size_t)idx * 8) = pk;
}

// 32 sorted nodes/tile: pure MFMA GEMM [32x128] @ [128 x 9*128] per type.
__global__ __launch_bounds__(256, 4) void kqv2(
    const float* __restrict__ x, const int* __restrict__ nlist_,
    const int* __restrict__ stype_s, const short* __restrict__ PW2,
    const float* __restrict__ PB,
    unsigned short* __restrict__ kn_s, unsigned short* __restrict__ qa_s,
    unsigned short* __restrict__ vm_s, int N) {
    __shared__ short af_l[2][4][64][8];        // 8 KB
    __shared__ unsigned short ob[32][128];     // 8 KB
    __shared__ int st_l[32];
    const int tid = threadIdx.x;
    const int sp0 = blockIdx.x * 32;
    if (tid < 32) {
        int sp = sp0 + tid;
        st_l[tid] = stype_s[sp < N ? sp : N - 1];
    }
    {
        int i = tid >> 3;
        int d0 = (tid & 7) * 16;
        int sp = sp0 + i;
        int nid = nlist_[sp < N ? sp : N - 1];
        const float* xr = x + (size_t)nid * 128 + d0;
        float4 f0 = *reinterpret_cast<const float4*>(xr);
        float4 f1 = *reinterpret_cast<const float4*>(xr + 4);
        float4 f2 = *reinterpret_cast<const float4*>(xr + 8);
        float4 f3 = *reinterpret_cast<const float4*>(xr + 12);
        int m = i >> 4, rr = i & 15;
        int ks = d0 >> 5;
        int sub = (d0 >> 3) & 3;
        uint4 p0, p1;
        p0.x = pack2(f0.x, f0.y); p0.y = pack2(f0.z, f0.w);
        p0.z = pack2(f1.x, f1.y); p0.w = pack2(f1.z, f1.w);
        p1.x = pack2(f2.x, f2.y); p1.y = pack2(f2.z, f2.w);
        p1.z = pack2(f3.x, f3.y); p1.w = pack2(f3.z, f3.w);
        *reinterpret_cast<uint4*>(&af_l[m][ks][sub * 16 + rr][0]) = p0;
        *reinterpret_cast<uint4*>(&af_l[m][ks][(sub + 1) * 16 + rr][0]) = p1;
    }
    __syncthreads();

    const int lane = tid & 63, w = tid >> 6;
    const int col_l = lane & 15, rowg = lane >> 4;
    const int t0 = st_l[0], t1 = st_l[31];

    bf16x8 afr[2][4];
    #pragma unroll
    for (int m = 0; m < 2; ++m)
        #pragma unroll
        for (int ks = 0; ks < 4; ++ks)
            afr[m][ks] = *reinterpret_cast<const bf16x8*>(&af_l[m][ks][lane][0]);

    for (int set = 0; set < 9; ++set) {
        for (int t = t0; t <= t1; ++t) {
            #pragma unroll
            for (int c = 0; c < 2; ++c) {
                int ctg = w + c * 4;
                bf16x8 pf[4];
                #pragma unroll
                for (int ks = 0; ks < 4; ++ks)
                    pf[ks] = *reinterpret_cast<const bf16x8*>(
                        PW2 + ((size_t)((((set * 4 + t) * 8 + ctg) * 4 + ks) * 64 + lane)) * 8);
                float bval = PB[(set * 4 + t) * 128 + ctg * 16 + col_l];
                #pragma unroll
                for (int m = 0; m < 2; ++m) {
                    f32x4 acc = {0.f, 0.f, 0.f, 0.f};
                    #pragma unroll
                    for (int ks = 0; ks < 4; ++ks)
                        acc = __builtin_amdgcn_mfma_f32_16x16x32_bf16(afr[m][ks], pf[ks], acc, 0, 0, 0);
                    #pragma unroll
                    for (int j = 0; j < 4; ++j) {
                        int i = m * 16 + rowg * 4 + j;
                        if (st_l[i] == t)
                            ob[i][ctg * 16 + col_l] = f2bf(acc[j] + bval);
                    }
                }
            }
        }
        __syncthreads();
        {
            int i = tid >> 3, d0 = (tid & 7) * 16;
            int sp = sp0 + i;
            if (sp < N) {
                unsigned short* dst;
                if (set == 0) dst = kn_s + (size_t)sp * 128;
                else if (set <= 4) dst = qa_s + ((size_t)sp * 4 + (set - 1)) * 128;
                else dst = vm_s + ((size_t)sp * 4 + (set - 5)) * 128;
                *reinterpret_cast<uint4*>(dst + d0) = *reinterpret_cast<const uint4*>(&ob[i][d0]);
                *reinterpret_cast<uint4*>(dst + d0 + 8) = *reinterpret_cast<const uint4*>(&ob[i][d0 + 8]);
            }
        }
        __syncthreads();
    }
}

// One sorted node per 16 lanes. CSR edges; deferred-max online softmax; no atomics.
__global__ __launch_bounds__(256) void fused_edge_attn(
    const int2* __restrict__ ebuf, const int* __restrict__ row_start, const int* __restrict__ deg,
    const unsigned short* __restrict__ kn_s, const unsigned short* __restrict__ krte_bf,
    const unsigned short* __restrict__ qa_s, const unsigned short* __restrict__ vm_s,
    const unsigned short* __restrict__ vmrte_bf,
    float* __restrict__ aggr, int N) {
    int sp = blockIdx.x * 16 + (threadIdx.x >> 4);
    int l16 = threadIdx.x & 15;
    if (sp >= N) return;
    uint4 q[4];
    #pragma unroll
    for (int r = 0; r < 4; ++r)
        q[r] = *reinterpret_cast<const uint4*>(qa_s + ((size_t)sp * 4 + r) * 128 + l16 * 8);
    int start = row_start[sp], cnt = deg[sp];
    float m = -INFINITY, den = 0.f;
    float acc[8] = {0.f, 0.f, 0.f, 0.f, 0.f, 0.f, 0.f, 0.f};
    for (int i = 0; i < cnt; ++i) {
        int2 em = ebuf[start + i];
        int sps = em.x;
        int r = em.y & 3, tm = (em.y >> 2) & 255, st = (em.y >> 10) & 3;
        uint4 kv = *reinterpret_cast<const uint4*>(kn_s + (size_t)sps * 128 + l16 * 8);
        uint4 kr = *reinterpret_cast<const uint4*>(krte_bf + (size_t)(st * MAXLEN + tm) * 128 + l16 * 8);
        uint4 mv = *reinterpret_cast<const uint4*>(vm_s + ((size_t)sps * 4 + r) * 128 + l16 * 8);
        uint4 mr = *reinterpret_cast<const uint4*>(vmrte_bf + (size_t)((st * 4 + r) * MAXLEN + tm) * 128 + l16 * 8);
        uint4 qr = q[r];
        float p = 0.f;
        p += (bflo(kv.x) + bflo(kr.x)) * bflo(qr.x);
        p += (bfhi(kv.x) + bfhi(kr.x)) * bfhi(qr.x);
        p += (bflo(kv.y) + bflo(kr.y)) * bflo(qr.y);
        p += (bfhi(kv.y) + bfhi(kr.y)) * bfhi(qr.y);
        p += (bflo(kv.z) + bflo(kr.z)) * bflo(qr.z);
        p += (bfhi(kv.z) + bfhi(kr.z)) * bfhi(qr.z);
        p += (bflo(kv.w) + bflo(kr.w)) * bflo(qr.w);
        p += (bfhi(kv.w) + bfhi(kr.w)) * bfhi(qr.w);
        p += __shfl_xor(p, 1);
        if (p > m + 8.f) {  // deferred-max rescale (rare after warmup)
            float s = __expf(m - p);   // exp(-inf)=0 on first edge
            den *= s;
            #pragma unroll
            for (int k = 0; k < 8; ++k) acc[k] *= s;
            m = p;
        }
        float wgt = __expf(p - m);
        den += wgt;
        acc[0] += wgt * (bflo(mv.x) + bflo(mr.x));
        acc[1] += wgt * (bfhi(mv.x) + bfhi(mr.x));
        acc[2] += wgt * (bflo(mv.y) + bflo(mr.y));
        acc[3] += wgt * (bfhi(mv.y) + bfhi(mr.y));
        acc[4] += wgt * (bflo(mv.z) + bflo(mr.z));
        acc[5] += wgt * (bfhi(mv.z) + bfhi(mr.z));
        acc[6] += wgt * (bflo(mv.w) + bflo(mr.w));
        acc[7] += wgt * (bfhi(mv.w) + bfhi(mr.w));
    }
    float inv = den > 0.f ? 1.f / den : 0.f;
    float4 o0, o1;
    o0.x = acc[0] * inv; o0.y = acc[1] * inv; o0.z = acc[2] * inv; o0.w = acc[3] * inv;
    o1.x = acc[4] * inv; o1.y = acc[5] * inv; o1.z = acc[6] * inv; o1.w = acc[7] * inv;
    float* ap = aggr + (size_t)sp * 128 + l16 * 8;   // SORTED order
    *reinterpret_cast<float4*>(ap) = o0;
    *reinterpret_cast<float4*>(ap + 4) = o1;
}

// 32 sorted nodes/tile: gelu(aggr_sorted) -> MFMA Wa (single type) -> skip-blend -> LN -> scatter out
__global__ __launch_bounds__(256, 4) void update_sorted(
    const float* __restrict__ x, const int* __restrict__ nlist_,
    const int* __restrict__ stype_s, const short* __restrict__ PW2,
    const float* __restrict__ PB, const float* __restrict__ gamma,
    const float* __restrict__ beta, const float* __restrict__ skip,
    const float* __restrict__ aggr, float* __restrict__ out, int N) {
    __shared__ short af_l[2][4][64][8];   // 8 KB
    __shared__ float hs[32][128];         // 16 KB
    __shared__ int st_l[32];
    __shared__ int nid_l[32];
    const int tid = threadIdx.x;
    const int sp0 = blockIdx.x * 32;
    if (tid < 32) {
        int sp = sp0 + tid;
        int spc = sp < N ? sp : N - 1;
        st_l[tid] = stype_s[spc];
        nid_l[tid] = nlist_[spc];
    }
    {
        int i = tid >> 3;
        int d0 = (tid & 7) * 16;
        int sp = sp0 + i;
        int spc = sp < N ? sp : N - 1;
        const float* ar = aggr + (size_t)spc * 128 + d0;
        float g[16];
        #pragma unroll
        for (int c = 0; c < 4; ++c) {
            float4 f = *reinterpret_cast<const float4*>(ar + c * 4);
            g[c * 4 + 0] = 0.5f * f.x * (1.f + erff(f.x * 0.7071067811865476f));
            g[c * 4 + 1] = 0.5f * f.y * (1.f + erff(f.y * 0.7071067811865476f));
            g[c * 4 + 2] = 0.5f * f.z * (1.f + erff(f.z * 0.7071067811865476f));
            g[c * 4 + 3] = 0.5f * f.w * (1.f + erff(f.w * 0.7071067811865476f));
        }
        int m = i >> 4, rr = i & 15;
        int ks = d0 >> 5;
        int sub = (d0 >> 3) & 3;
        uint4 p0, p1;
        p0.x = pack2(g[0], g[1]);  p0.y = pack2(g[2], g[3]);
        p0.z = pack2(g[4], g[5]);  p0.w = pack2(g[6], g[7]);
        p1.x = pack2(g[8], g[9]);  p1.y = pack2(g[10], g[11]);
        p1.z = pack2(g[12], g[13]); p1.w = pack2(g[14], g[15]);
        *reinterpret_cast<uint4*>(&af_l[m][ks][sub * 16 + rr][0]) = p0;
        *reinterpret_cast<uint4*>(&af_l[m][ks][(sub + 1) * 16 + rr][0]) = p1;
    }
    __syncthreads();

    const int lane = tid & 63, w = tid >> 6;
    const int col_l = lane & 15, rowg = lane >> 4;
    const int t0 = st_l[0], t1 = st_l[31];

    bf16x8 afr[2][4];
    #pragma unroll
    for (int m = 0; m < 2; ++m)
        #pragma unroll
        for (int ks = 0; ks < 4; ++ks)
            afr[m][ks] = *reinterpret_cast<const bf16x8*>(&af_l[m][ks][lane][0]);

    for (int t = t0; t <= t1; ++t) {
        #pragma unroll
        for (int c = 0; c < 2; ++c) {
            int ctg = w + c * 4;
            bf16x8 pf[4];
            #pragma unroll
            for (int ks = 0; ks < 4; ++ks)
                pf[ks] = *reinterpret_cast<const bf16x8*>(
                    PW2 + ((size_t)((((9 * 4 + t) * 8 + ctg) * 4 + ks) * 64 + lane)) * 8);
            float bval = PB[(9 * 4 + t) * 128 + ctg * 16 + col_l];
            #pragma unroll
            for (int m = 0; m < 2; ++m) {
                f32x4 acc = {0.f, 0.f, 0.f, 0.f};
                #pragma unroll
                for (int ks = 0; ks < 4; ++ks)
                    acc = __builtin_amdgcn_mfma_f32_16x16x32_bf16(afr[m][ks], pf[ks], acc, 0, 0, 0);
                #pragma unroll
                for (int j = 0; j < 4; ++j) {
                    int i = m * 16 + rowg * 4 + j;
                    if (st_l[i] == t)
                        hs[i][ctg * 16 + col_l] = acc[j] + bval;
                }
            }
        }
    }
    __syncthreads();

    // LayerNorm: row i handled by 8 lanes (16 cols each)
    {
        int i = tid >> 3;
        int d0 = (tid & 7) * 16;
        int sp = sp0 + i;
        int nid = nid_l[i];
        int t = st_l[i];
        float alpha = 1.f / (1.f + expf(-skip[t]));
        const float* xr = x + (size_t)nid * 128 + d0;
        float hv[16];
        float s1 = 0.f, s2 = 0.f;
        #pragma unroll
        for (int c = 0; c < 4; ++c) {
            float4 xf = *reinterpret_cast<const float4*>(xr + c * 4);
            float4 tf;
            tf.x = hs[i][d0 + c * 4 + 0]; tf.y = hs[i][d0 + c * 4 + 1];
            tf.z = hs[i][d0 + c * 4 + 2]; tf.w = hs[i][d0 + c * 4 + 3];
            hv[c * 4 + 0] = tf.x * alpha + xf.x * (1.f - alpha);
            hv[c * 4 + 1] = tf.y * alpha + xf.y * (1.f - alpha);
            hv[c * 4 + 2] = tf.z * alpha + xf.z * (1.f - alpha);
            hv[c * 4 + 3] = tf.w * alpha + xf.w * (1.f - alpha);
            #pragma unroll
            for (int j = 0; j < 4; ++j) { s1 += hv[c * 4 + j]; s2 += hv[c * 4 + j] * hv[c * 4 + j]; }
        }
        #pragma unroll
        for (int off = 1; off < 8; off <<= 1) {
            s1 += __shfl_xor(s1, off);
            s2 += __shfl_xor(s2, off);
        }
        float mu = s1 * (1.f / 128.f);
        float var = s2 * (1.f / 128.f) - mu * mu;
        float inv = 1.f / sqrtf(var + 1e-5f);
        if (sp < N) {
            float* orow = out + (size_t)nid * 128 + d0;
            const float* gr = gamma + t * 128 + d0;
            const float* br = beta + t * 128 + d0;
            #pragma unroll
            for (int c = 0; c < 4; ++c) {
                float4 gf = *reinterpret_cast<const float4*>(gr + c * 4);
                float4 bf = *reinterpret_cast<const float4*>(br + c * 4);
                float4 of;
                of.x = (hv[c * 4 + 0] - mu) * inv * gf.x + bf.x;
                of.y = (hv[c * 4 + 1] - mu) * inv * gf.y + bf.y;
                of.z = (hv[c * 4 + 2] - mu) * inv * gf.z + bf.z;
                of.w = (hv[c * 4 + 3] - mu) * inv * gf.w + bf.w;
                *reinterpret_cast<float4*>(orow + c * 4) = of;
            }
        }
    }
}

extern "C" void kernel_launch(void* const* d_in, const int* in_sizes, int n_in,
                              void* d_out, int out_size, void* d_ws, size_t ws_size,
                              hipStream_t stream) {
    const float* node_inp = (const float*)d_in[0];
    const int*   node_type = (const int*)d_in[1];
    const int*   edge_index = (const int*)d_in[2];
    const int*   edge_type = (const int*)d_in[3];
    const int*   edge_time = (const int*)d_in[4];
    const float* Wk = (const float*)d_in[5];
    const float* bk = (const float*)d_in[6];
    const float* Wq = (const float*)d_in[7];
    const float* bq = (const float*)d_in[8];
    const float* Wv = (const float*)d_in[9];
    const float* bv = (const float*)d_in[10];
    const float* Wa = (const float*)d_in[11];
    const float* ba = (const float*)d_in[12];
    const float* gamma = (const float*)d_in[13];
    const float* beta = (const float*)d_in[14];
    const float* rel_pri = (const float*)d_in[15];
    const float* rel_att = (const float*)d_in[16];
    const float* rel_msg = (const float*)d_in[17];
    const float* skip = (const float*)d_in[18];
    const float* rte_W = (const float*)d_in[19];
    const float* rte_b = (const float*)d_in[20];

    int N = in_sizes[0] / 128;   // 50000
    int E = in_sizes[3];         // 600000

    char* base = (char*)d_ws;
    float* aggr = (float*)base;               base += (size_t)N * 128 * 4;
    unsigned short* kn_s = (unsigned short*)base;     base += (size_t)N * 128 * 2;
    unsigned short* qa_s = (unsigned short*)base;     base += (size_t)N * 4 * 128 * 2;
    unsigned short* vm_s = (unsigned short*)base;     base += (size_t)N * 4 * 128 * 2;
    unsigned short* krte_bf = (unsigned short*)base;  base += (size_t)NT * MAXLEN * 128 * 2;
    unsigned short* vmrte_bf = (unsigned short*)base; base += (size_t)NT * NR * MAXLEN * 128 * 2;
    short* PW2 = (short*)base;                base += (size_t)10 * NT * 128 * 128 * 2;
    float* PB = (float*)base;                 base += (size_t)10 * NT * 128 * 4;
    int* deg = (int*)base;                    base += (size_t)N * 4;
    int* cursor = (int*)base;                 base += (size_t)N * 4;
    int* excl = (int*)base;                   base += (size_t)N * 4;
    int* row_start = (int*)base;              base += (size_t)N * 4;
    int* nlist = (int*)base;                  base += (size_t)N * 4;
    int* spos = (int*)base;                   base += (size_t)N * 4;
    int* stype_s = (int*)base;                base += (size_t)N * 4;
    int* bsum = (int*)base;                   base += 256 * 4;
    int* tcnt = (int*)base;                   base += 4 * 4;
    int* tcur = (int*)base;                   base += 4 * 4;
    int* tbase = (int*)base;                  base += 4 * 4;
    base = (char*)(((size_t)base + 15) & ~(size_t)15);
    int2* ebuf = (int2*)base;                 base += (size_t)E * 8;

    int nb = (N + 255) / 256;   // 196
    int ng = (N + 255) / 256;

    zero_kernel<<<256, 256, 0, stream>>>(deg, cursor, tcnt, tcur, N);
    count_types<<<ng, 256, 0, stream>>>(node_type, tcnt, N);
    base_kernel<<<1, 64, 0, stream>>>(tcnt, tbase);
    place_nodes<<<ng, 256, 0, stream>>>(node_type, tbase, tcur, nlist, spos, stype_s, N);
    deg_kernel<<<1024, 256, 0, stream>>>(edge_index, spos, deg, E);
    scanA<<<nb, 256, 0, stream>>>(deg, excl, bsum, N);
    scanB<<<1, 256, 0, stream>>>(bsum, nb);
    scanC<<<nb, 256, 0, stream>>>(excl, bsum, row_start, N);
    scatter_kernel<<<1024, 256, 0, stream>>>(edge_index, edge_type, edge_time, spos, tbase,
                                             row_start, cursor, ebuf, E);
    dim3 gt(MAXLEN, NT);
    rte_tables<<<gt, 128, 0, stream>>>(rte_W, rte_b, Wk, Wv, rel_msg, krte_bf, vmrte_bf);
    pack_w9<<<340, 256, 0, stream>>>(Wk, Wq, Wv, Wa, bk, bq, bv, ba,
                                     rel_att, rel_msg, rel_pri, PW2, PB);
    kqv2<<<(N + 31) / 32, 256, 0, stream>>>(node_inp, nlist, stype_s, PW2, PB,
                                            kn_s, qa_s, vm_s, N);
    fused_edge_attn<<<(N + 15) / 16, 256, 0, stream>>>(ebuf, row_start, deg,
                                                       kn_s, krte_bf, qa_s, vm_s, vmrte_bf,
                                                       aggr, N);
    update_sorted<<<(N + 31) / 32, 256, 0, stream>>>(node_inp, nlist, stype_s, PW2, PB,
                                                     gamma, beta, skip, aggr, (float*)d_out, N);
}